// Round 14
// baseline (127.429 us; speedup 1.0000x reference)
//
#include <hip/hip_runtime.h>
#include <hip/hip_bf16.h>
#include <stdint.h>

// ---------- types ----------
using short8  = __attribute__((ext_vector_type(8))) short;
using f32x4   = __attribute__((ext_vector_type(4))) float;
using f32x16  = __attribute__((ext_vector_type(16))) float;

__device__ inline unsigned short f2bf(float f) {
    union { float f; unsigned int u; } v; v.f = f;
    unsigned int u = v.u;
    unsigned int r = (u + 0x7FFFu + ((u >> 16) & 1u)) >> 16;   // RNE
    return (unsigned short)r;
}

__device__ inline unsigned short bfu(float f) {
    __hip_bfloat16 h = __float2bfloat16(f);
    union { __hip_bfloat16 h; unsigned short u; } c; c.h = h;
    return c.u;
}

__device__ inline float bf2f(unsigned short u) {
    union { unsigned int u; float f; } v; v.u = (unsigned int)u << 16;
    return v.f;
}

// pack two floats to bf16 pair (compiler fuses to v_cvt_pk_bf16_f32)
__device__ inline unsigned int bfpk(float lo, float hi) {
    return (unsigned int)bfu(lo) | ((unsigned int)bfu(hi) << 16);
}

__device__ inline f32x4 mfma16(short8 a, short8 b, f32x4 c) {
    return __builtin_amdgcn_mfma_f32_16x16x32_bf16(a, b, c, 0, 0, 0);
}
__device__ inline f32x16 mfma32(short8 a, short8 b, f32x16 c) {
    return __builtin_amdgcn_mfma_f32_32x32x16_bf16(a, b, c, 0, 0, 0);
}

// async global->LDS, 16B per lane: LDS dest = wave-uniform base + lane*16
__device__ inline void gld16(const void* g, void* l) {
    __builtin_amdgcn_global_load_lds(
        (const __attribute__((address_space(1))) unsigned int*)g,
        (__attribute__((address_space(3))) unsigned int*)l, 16, 0, 0);
}

// B=2, S=2048, D=1024, H=16, DH=64
#define SEQ 2048
#define DIM 1024
#define NH  16
#define DH  64
#define MROWS 4096      // B*S
#define OHALF 4194304   // B*S*DIM elems per split half
#define LHALF 65536     // B*NH*SEQ elems per split half

// ---------------------------------------------------------------------------
// k0: weight fp32 [k][n] -> bf16 Wt [n][k]  (transpose + convert), 64x64 tiles
// ---------------------------------------------------------------------------
__global__ __launch_bounds__(256) void wcvt_kernel(
    const float* __restrict__ W0, const float* __restrict__ W1,
    const float* __restrict__ W2, const float* __restrict__ W3,
    unsigned short* __restrict__ Wt)
{
    __shared__ unsigned short tile[64][72];
    const float* W = (blockIdx.y == 0) ? W0 : (blockIdx.y == 1) ? W1
                   : (blockIdx.y == 2) ? W2 : W3;
    unsigned short* out = Wt + (size_t)blockIdx.y * DIM * DIM;
    const int t  = threadIdx.x;
    const int tk = blockIdx.x >> 4, tn = blockIdx.x & 15;
    const int k0 = tk * 64, n0 = tn * 64;

    #pragma unroll
    for (int j = 0; j < 4; ++j) {
        int c = t + j * 256;
        int r = c >> 4, c4 = c & 15;
        float4 v = *(const float4*)(W + (size_t)(k0 + r) * DIM + n0 + c4 * 4);
        tile[c4 * 4 + 0][r] = f2bf(v.x);
        tile[c4 * 4 + 1][r] = f2bf(v.y);
        tile[c4 * 4 + 2][r] = f2bf(v.z);
        tile[c4 * 4 + 3][r] = f2bf(v.w);
    }
    __syncthreads();
    #pragma unroll
    for (int j = 0; j < 2; ++j) {
        int c = t + j * 256;
        int r = c >> 3, c8 = c & 7;
        *(short8*)(out + (size_t)(n0 + r) * DIM + k0 + c8 * 8) =
            *(const short8*)&tile[r][c8 * 8];
    }
}

// ---------------------------------------------------------------------------
// k0b: mask scan. pos[b][s] = compact index (-1 if masked); cnt[b] = #live.
//      pos/cnt live in d_out scratch (outproj overwrites d_out last).
// ---------------------------------------------------------------------------
__global__ __launch_bounds__(256) void mask_scan_kernel(
    const float* __restrict__ mask, int* __restrict__ pos, int* __restrict__ cnt)
{
    __shared__ int sums[256];
    const int b = blockIdx.x, t = threadIdx.x;
    const float* m = mask + (size_t)b * SEQ;
    int flags[8], s = 0;
    #pragma unroll
    for (int i = 0; i < 8; ++i) {
        flags[i] = (m[t * 8 + i] == 0.0f) ? 1 : 0;
        s += flags[i];
    }
    sums[t] = s;
    __syncthreads();
    if (t == 0) {
        int acc = 0;
        for (int i = 0; i < 256; ++i) { int x = sums[i]; sums[i] = acc; acc += x; }
        cnt[b] = acc;
    }
    __syncthreads();
    int base = sums[t];
    #pragma unroll
    for (int i = 0; i < 8; ++i) {
        pos[(size_t)b * SEQ + t * 8 + i] = flags[i] ? base : -1;
        base += flags[i];
    }
}

// ---------------------------------------------------------------------------
// k0c: zero the tail pad slots of the last partial 32-tile in Kh / Vt.
// ---------------------------------------------------------------------------
__global__ __launch_bounds__(256) void pad_kernel(
    const int* __restrict__ cnt, unsigned short* __restrict__ Kh,
    unsigned short* __restrict__ Vt)
{
    const int bh = blockIdx.x, b = bh >> 4;
    const int c = cnt[b];
    if ((c & 31) == 0) return;
    const int base = c & ~31;
    const int t = threadIdx.x;
    short8 z = {0, 0, 0, 0, 0, 0, 0, 0};
    *(short8*)(Kh + ((size_t)bh * SEQ + base + (t >> 3)) * DH + (t & 7) * 8) = z;
    *(short8*)(Vt + (size_t)bh * DH * SEQ + (size_t)(t >> 2) * SEQ + base + (t & 3) * 8) = z;
}

// ---------------------------------------------------------------------------
// k1: X fp32 -> bf16 (3 inputs, flat copy). grid (2048, 3)
// ---------------------------------------------------------------------------
__global__ __launch_bounds__(256) void xcvt_kernel(
    const float* __restrict__ Xq, const float* __restrict__ Xk,
    const float* __restrict__ Xv, unsigned short* __restrict__ Xbf)
{
    const int zz = blockIdx.y;
    const float* src = (zz == 0) ? Xq : (zz == 1) ? Xk : Xv;
    size_t i8 = ((size_t)blockIdx.x * 256 + threadIdx.x) * 8;
    float4 v0 = *(const float4*)(src + i8);
    float4 v1 = *(const float4*)(src + i8 + 4);
    union { unsigned int u[4]; short8 s8; } p;
    p.u[0] = bfpk(v0.x, v0.y); p.u[1] = bfpk(v0.z, v0.w);
    p.u[2] = bfpk(v1.x, v1.y); p.u[3] = bfpk(v1.z, v1.w);
    *(short8*)(Xbf + (size_t)zz * MROWS * DIM + i8) = p.s8;
}

// ---------------------------------------------------------------------------
// k2: projection GEMM. BF16A: both operands staged via global_load_lds DMA
//     (linear LDS dest + source-address pre-swizzle; XOR ds_read unchanged).
//     z=0 -> Qh (scaled 0.125*log2e); z=1 -> Kh COMPACTED; z=2 -> Vt
//     COMPACTED transposed.
// ---------------------------------------------------------------------------
template<bool BF16A>
__global__ __launch_bounds__(256, 3) void proj_kernel(
    const unsigned short* __restrict__ Xbf,
    const float* __restrict__ Xq, const float* __restrict__ Xk, const float* __restrict__ Xv,
    const unsigned short* __restrict__ Wt,
    const float* __restrict__ bq, const float* __restrict__ bk, const float* __restrict__ bv,
    const int* __restrict__ pos,
    unsigned short* __restrict__ Qh, unsigned short* __restrict__ Kh,
    unsigned short* __restrict__ Vt)
{
    __shared__ unsigned short Al[128][64];
    __shared__ unsigned short Bl[128][64];

    const int bid = blockIdx.x;
    const int z = bid >> 8;
    const int p = bid & 255;
    const int qq = p >> 3;
    const int mb = (p & 7) | ((qq & 3) << 3);   // 0..31
    const int nb = qq >> 2;                     // 0..7
    const int m0 = mb * 128, n0 = nb * 128;

    const unsigned short* W = Wt + (size_t)z * DIM * DIM;
    const float* bias = (z == 0) ? bq : (z == 1) ? bk : bv;

    const int t = threadIdx.x, lane = t & 63, w = t >> 6;
    const int l16 = lane & 15, hi = lane >> 4;
    const int wm = w >> 1, wn = w & 1;

    f32x4 zero4 = {0.f, 0.f, 0.f, 0.f};
    f32x4 acc[4][4];
    #pragma unroll
    for (int i = 0; i < 4; ++i)
        #pragma unroll
        for (int j = 0; j < 4; ++j) acc[i][j] = zero4;

    if constexpr (BF16A) {
        const unsigned short* Abase = Xbf + (size_t)z * MROWS * DIM + (size_t)m0 * DIM;
        const unsigned short* Bbase = W + (size_t)n0 * DIM;
        const unsigned short* asrc[4];
        const unsigned short* bsrc[4];
        unsigned short* adst[4];
        unsigned short* bdst[4];
        #pragma unroll
        for (int pass = 0; pass < 4; ++pass) {
            int c = pass * 256 + t;
            int row = c >> 3;
            int colg = (((c & 7) ^ (row & 7)) * 8);
            asrc[pass] = Abase + (size_t)row * DIM + colg;
            bsrc[pass] = Bbase + (size_t)row * DIM + colg;
            adst[pass] = &Al[0][0] + c * 8;
            bdst[pass] = &Bl[0][0] + c * 8;
        }
        for (int kt = 0; kt < DIM / 64; ++kt) {
            const int k0 = kt * 64;
            #pragma unroll
            for (int pass = 0; pass < 4; ++pass) {
                gld16(asrc[pass] + k0, adst[pass]);
                gld16(bsrc[pass] + k0, bdst[pass]);
            }
            asm volatile("s_waitcnt vmcnt(0)" ::: "memory");
            __syncthreads();
            #pragma unroll
            for (int kc = 0; kc < 2; ++kc) {
                short8 af[4], bfv[4];
                #pragma unroll
                for (int i = 0; i < 4; ++i) {
                    int ra = wm * 64 + i * 16 + l16;
                    af[i] = *(const short8*)&Al[ra][(kc * 32 + hi * 8) ^ ((ra & 7) << 3)];
                }
                #pragma unroll
                for (int j = 0; j < 4; ++j) {
                    int rb = wn * 64 + j * 16 + l16;
                    bfv[j] = *(const short8*)&Bl[rb][(kc * 32 + hi * 8) ^ ((rb & 7) << 3)];
                }
                #pragma unroll
                for (int i = 0; i < 4; ++i)
                    #pragma unroll
                    for (int j = 0; j < 4; ++j)
                        acc[i][j] = mfma16(af[i], bfv[j], acc[i][j]);
            }
            __syncthreads();
        }
    } else {
        const int row2 = t >> 1, part = t & 1;
        const int swz = (row2 & 7) << 3;
        const int cb = part * 32;
        const float* X = (z == 0) ? Xq : (z == 1) ? Xk : Xv;
        const float* Asrc_f = X + (size_t)(m0 + row2) * DIM + cb;
        const unsigned short* Bsrc = W + (size_t)(n0 + row2) * DIM + cb;

        short8 na[4], nbv[4];
        auto ldA = [&](int k0, int i) {
            float4 f0 = *(const float4*)(Asrc_f + k0 + i * 8);
            float4 f1 = *(const float4*)(Asrc_f + k0 + i * 8 + 4);
            union { unsigned int u[4]; short8 s8; } pk;
            pk.u[0] = bfpk(f0.x, f0.y); pk.u[1] = bfpk(f0.z, f0.w);
            pk.u[2] = bfpk(f1.x, f1.y); pk.u[3] = bfpk(f1.z, f1.w);
            return pk.s8;
        };
        #pragma unroll
        for (int i = 0; i < 4; ++i) {
            na[i]  = ldA(0, i);
            nbv[i] = *(const short8*)(Bsrc + i * 8);
        }
        #pragma unroll
        for (int i = 0; i < 4; ++i) {
            *(short8*)&Al[row2][(cb + i * 8) ^ swz] = na[i];
            *(short8*)&Bl[row2][(cb + i * 8) ^ swz] = nbv[i];
        }
        __syncthreads();
        for (int kt = 0; kt < DIM / 64; ++kt) {
            if (kt < DIM / 64 - 1) {
                const int k0n = (kt + 1) * 64;
                #pragma unroll
                for (int i = 0; i < 4; ++i) {
                    na[i]  = ldA(k0n, i);
                    nbv[i] = *(const short8*)(Bsrc + k0n + i * 8);
                }
            }
            #pragma unroll
            for (int kc = 0; kc < 2; ++kc) {
                short8 af[4], bfv[4];
                #pragma unroll
                for (int i = 0; i < 4; ++i) {
                    int ra = wm * 64 + i * 16 + l16;
                    af[i] = *(const short8*)&Al[ra][(kc * 32 + hi * 8) ^ ((ra & 7) << 3)];
                }
                #pragma unroll
                for (int j = 0; j < 4; ++j) {
                    int rb = wn * 64 + j * 16 + l16;
                    bfv[j] = *(const short8*)&Bl[rb][(kc * 32 + hi * 8) ^ ((rb & 7) << 3)];
                }
                #pragma unroll
                for (int i = 0; i < 4; ++i)
                    #pragma unroll
                    for (int j = 0; j < 4; ++j)
                        acc[i][j] = mfma16(af[i], bfv[j], acc[i][j]);
            }
            __syncthreads();
            if (kt < DIM / 64 - 1) {
                #pragma unroll
                for (int i = 0; i < 4; ++i) {
                    *(short8*)&Al[row2][(cb + i * 8) ^ swz] = na[i];
                    *(short8*)&Bl[row2][(cb + i * 8) ^ swz] = nbv[i];
                }
            }
            __syncthreads();
        }
    }

    float bj[4];
    #pragma unroll
    for (int j = 0; j < 4; ++j) bj[j] = bias[n0 + wn * 64 + j * 16 + l16];

    if (z == 2) {
        #pragma unroll
        for (int i = 0; i < 4; ++i) {
            int mrow0 = m0 + wm * 64 + i * 16 + hi * 4;
            int bb = mrow0 >> 11, s = mrow0 & (SEQ - 1);
            #pragma unroll
            for (int r = 0; r < 4; ++r) {
                int p_ = pos[(size_t)bb * SEQ + s + r];
                if (p_ < 0) continue;
                #pragma unroll
                for (int j = 0; j < 4; ++j) {
                    int n = n0 + wn * 64 + j * 16 + l16;
                    int dn = n & 63, hh = n >> 6;
                    int scol = (p_ & ~31) | ((((p_ >> 3) & 3) ^ ((dn >> 1) & 3)) << 3)
                             | (p_ & 7);
                    Vt[((size_t)(bb * NH + hh) * DH + dn) * SEQ + scol] =
                        bfu(acc[i][j][r] + bj[j]);
                }
            }
        }
    } else if (z == 1) {
        #pragma unroll
        for (int i = 0; i < 4; ++i) {
            int mrow0 = m0 + wm * 64 + i * 16 + hi * 4;
            int bb = mrow0 >> 11, s = mrow0 & (SEQ - 1);
            #pragma unroll
            for (int r = 0; r < 4; ++r) {
                int p_ = pos[(size_t)bb * SEQ + s + r];
                if (p_ < 0) continue;
                #pragma unroll
                for (int j = 0; j < 4; ++j) {
                    int n = n0 + wn * 64 + j * 16 + l16;
                    int hh = n >> 6, d = n & 63;
                    int dsw = (d & 7) | ((((d >> 3) ^ (p_ & 7)) & 7) << 3);
                    Kh[((size_t)(bb * NH + hh) * SEQ + p_) * DH + dsw] =
                        bfu(acc[i][j][r] + bj[j]);
                }
            }
        }
    } else {
        const float sc = 0.125f * 1.4426950408889634f;   // fold 1/sqrt(DH)*log2e
        #pragma unroll
        for (int i = 0; i < 4; ++i) {
            #pragma unroll
            for (int j = 0; j < 4; ++j) {
                int n = n0 + wn * 64 + j * 16 + l16;
                int hh = n >> 6, d = n & 63;
                #pragma unroll
                for (int r = 0; r < 4; ++r) {
                    int mrow = m0 + wm * 64 + i * 16 + hi * 4 + r;
                    int bb = mrow >> 11, s = mrow & (SEQ - 1);
                    Qh[((size_t)(bb * NH + hh) * SEQ + s) * DH + d] =
                        bfu((acc[i][j][r] + bj[j]) * sc);
                }
            }
        }
    }
}

// ---------------------------------------------------------------------------
// k3: flash attention over COMPACTED K/V. 4 waves x 32 q (QBLK=128),
//     KVBLK=32, LDS 16KB -> 4 blocks/CU in the co-residency pool.
//     Grid (32,16,2) = 1024 blocks. Each thread DMAs one K chunk AND one V
//     chunk per tile. SPLIT partials (pure sums) combined in outproj.
// ---------------------------------------------------------------------------
template<bool SPLIT>
__global__ __launch_bounds__(256) void attn_kernel(
    const unsigned short* __restrict__ Qh,
    const unsigned short* __restrict__ Kh,
    const unsigned short* __restrict__ Vtp,
    const int* __restrict__ cntbuf,
    unsigned short* __restrict__ AO,
    unsigned short* __restrict__ Opart,
    float* __restrict__ lpart)
{
    __shared__ unsigned short Kl[2][32 * 64];    // [s(32)][d(64)]
    __shared__ unsigned short Vl[2][64 * 32];    // [d(64)][s(32)]

    const int t = threadIdx.x, lane = t & 63, w = t >> 6;   // w 0..3
    const int l31 = lane & 31, h32 = lane >> 5;
    const int bh = blockIdx.x, b = bh >> 4, h = bh & (NH - 1);
    const int q0 = blockIdx.y * 128 + w * 32;
    const int half = SPLIT ? blockIdx.z : 0;

    const int cnt = cntbuf[b];
    const int NTt = (cnt + 31) >> 5;             // total tiles
    const int NTh0 = (NTt + 1) >> 1;
    const int t0   = (SPLIT && half) ? NTh0 : 0;
    const int myNT = SPLIT ? (half ? NTt - NTh0 : NTh0) : NTt;

    const unsigned short* Q = Qh + (size_t)bh * SEQ * DH;
    const unsigned short* K = Kh + (size_t)bh * SEQ * DH;
    const unsigned short* V = Vtp + (size_t)bh * DH * SEQ;

    short8 qf[4];
    #pragma unroll
    for (int ds = 0; ds < 4; ++ds)
        qf[ds] = *(const short8*)(Q + (size_t)(q0 + l31) * DH + ds * 16 + h32 * 8);

    f32x16 o[2], ol;
    #pragma unroll
    for (int r = 0; r < 16; ++r) { o[0][r] = 0.f; o[1][r] = 0.f; ol[r] = 0.f; }

    // prologue: DMA tile t0 (each thread: 1 K chunk + 1 V chunk)
    {
        const int kb0 = t0 * 32;
        gld16(K + (size_t)(kb0 + (t >> 3)) * DH + (t & 7) * 8, &Kl[0][t * 8]);
        gld16(V + (size_t)(t >> 2) * SEQ + kb0 + (t & 3) * 8,  &Vl[0][t * 8]);
    }
    asm volatile("s_waitcnt vmcnt(0)" ::: "memory");
    __syncthreads();

    for (int it = 0; it < myNT; ++it) {
        const int tile = t0 + it;
        const int cur = it & 1;
        const int kb = tile * 32;
        const int nt_ = (it + 1 < myNT) ? (tile + 1) : t0;
        const int nkb = nt_ * 32;

        gld16(K + (size_t)(nkb + (t >> 3)) * DH + (t & 7) * 8, &Kl[cur ^ 1][t * 8]);
        gld16(V + (size_t)(t >> 2) * SEQ + nkb + (t & 3) * 8,  &Vl[cur ^ 1][t * 8]);

        short8 wf[2];
        if (kb + 32 <= cnt) {
            #pragma unroll
            for (int ss = 0; ss < 2; ++ss)
                #pragma unroll
                for (int e = 0; e < 8; ++e) wf[ss][e] = (short)0x3F80;
        } else {
            #pragma unroll
            for (int ss = 0; ss < 2; ++ss)
                #pragma unroll
                for (int e = 0; e < 8; ++e)
                    wf[ss][e] = (short)((kb + ss * 16 + h32 * 8 + e < cnt) ? 0x3F80 : 0);
        }

        f32x16 st;
        #pragma unroll
        for (int r = 0; r < 16; ++r) st[r] = 0.f;
        __builtin_amdgcn_s_setprio(1);
        #pragma unroll
        for (int ds = 0; ds < 4; ++ds) {
            short8 kfr = *(const short8*)
                &Kl[cur][l31 * 64 + (((ds * 2 + h32) ^ (l31 & 7)) * 8)];
            st = mfma32(kfr, qf[ds], st);
        }
        __builtin_amdgcn_s_setprio(0);

        #pragma unroll
        for (int r = 0; r < 16; ++r) st[r] = exp2f(st[r]);

        short8 pa[2];
        #pragma unroll
        for (int ss = 0; ss < 2; ++ss) {
            const int rb = ss * 8;
            unsigned int a0 = bfpk(st[rb + 0], st[rb + 1]);
            unsigned int a1 = bfpk(st[rb + 2], st[rb + 3]);
            unsigned int b0 = bfpk(st[rb + 4], st[rb + 5]);
            unsigned int b1 = bfpk(st[rb + 6], st[rb + 7]);
            asm volatile("v_permlane32_swap_b32 %0, %1" : "+v"(a0), "+v"(b0));
            asm volatile("v_permlane32_swap_b32 %0, %1" : "+v"(a1), "+v"(b1));
            union { unsigned int u[4]; short8 s8; } up;
            up.u[0] = a0; up.u[1] = a1; up.u[2] = b0; up.u[3] = b1;
            pa[ss] = up.s8;
        }

        __builtin_amdgcn_s_setprio(1);
        #pragma unroll
        for (int ss = 0; ss < 2; ++ss) {
            #pragma unroll
            for (int dblk = 0; dblk < 2; ++dblk) {
                int vrow = dblk * 32 + l31;
                short8 vfr = *(const short8*)
                    &Vl[cur][vrow * 32 + (((ss * 2 + h32) ^ ((l31 >> 1) & 3)) * 8)];
                o[dblk] = mfma32(pa[ss], vfr, o[dblk]);
            }
            ol = mfma32(pa[ss], wf[ss], ol);
        }
        __builtin_amdgcn_s_setprio(0);

        asm volatile("s_waitcnt vmcnt(0)" ::: "memory");
        __syncthreads();
    }
    asm volatile("s_waitcnt vmcnt(0)" ::: "memory");   // covers myNT==0 prologue DMA

    if constexpr (SPLIT) {
        #pragma unroll
        for (int dblk = 0; dblk < 2; ++dblk) {
            #pragma unroll
            for (int r = 0; r < 16; ++r) {
                int q = (r & 3) + 8 * (r >> 2) + 4 * h32;
                Opart[(size_t)half * OHALF + (size_t)(b * SEQ + q0 + q) * DIM
                      + h * DH + dblk * 32 + l31] = bfu(o[dblk][r]);
            }
        }
        if (l31 == 0) {
            #pragma unroll
            for (int r = 0; r < 16; ++r) {
                int q = (r & 3) + 8 * (r >> 2) + 4 * h32;
                lpart[(size_t)half * LHALF + bh * SEQ + q0 + q] = ol[r];
            }
        }
    } else {
        float rcl[16];
        #pragma unroll
        for (int r = 0; r < 16; ++r) rcl[r] = 1.0f / ol[r];
        #pragma unroll
        for (int dblk = 0; dblk < 2; ++dblk) {
            #pragma unroll
            for (int r = 0; r < 16; ++r) {
                int q = (r & 3) + 8 * (r >> 2) + 4 * h32;
                AO[(size_t)(b * SEQ + q0 + q) * DIM + h * DH + dblk * 32 + l31] =
                    bfu(o[dblk][r] * rcl[r]);
            }
        }
    }
}

// ---------------------------------------------------------------------------
// k4: output GEMM, 128x64 tiles -> 512 blocks. SPLIT fuses the half-combine
//     ((O0+O1)/(l0+l1)) into A-staging. Overwrites ALL of d_out (including
//     the pos/cnt scratch carved from it).
// ---------------------------------------------------------------------------
template<bool SPLIT>
__global__ __launch_bounds__(256, 3) void outproj_kernel(
    const unsigned short* __restrict__ Op0, const float* __restrict__ lpart,
    const unsigned short* __restrict__ W,
    const float* __restrict__ bias, float* __restrict__ Out)
{
    __shared__ unsigned short Al[128][64];
    __shared__ unsigned short Bl[64][64];

    const int p = blockIdx.x;                   // 0..511
    const int qq = p >> 3;                      // 0..63
    const int mb = (p & 7) | ((qq & 3) << 3);   // 0..31 ; p%8 = mb%8 (XCD)
    const int nb = qq >> 2;                     // 0..15
    const int m0 = mb * 128, n0 = nb * 64;

    const int t = threadIdx.x, lane = t & 63, w = t >> 6;
    const int l16 = lane & 15, hi = lane >> 4;
    const int wm = w >> 1, wn = w & 1;
    const int row2 = t >> 1, part = t & 1;
    const int swzA = (row2 & 7) << 3;
    const int cb = part * 32;
    const int row4 = t >> 2, part4 = t & 3;
    const int swzB = (row4 & 7) << 3;
    const int cb4 = part4 * 16;

    const int arow = m0 + row2;
    const int bb = arow >> 11, sA = arow & (SEQ - 1);
    const unsigned short* Asrc = Op0 + (size_t)arow * DIM + cb;
    const unsigned short* Bsrc = W + (size_t)(n0 + row4) * DIM + cb4;

    f32x4 zero4 = {0.f, 0.f, 0.f, 0.f};
    f32x4 acc[4][2];
    #pragma unroll
    for (int i = 0; i < 4; ++i) { acc[i][0] = zero4; acc[i][1] = zero4; }

    short8 o0[4], o1[4], nbv[2];
    float rlv = 0.f;

    auto load_kt = [&](int kt) {
        const int k0 = kt * 64;
        if constexpr (SPLIT) {
            size_t li = (size_t)(bb * NH + kt) * SEQ + sA;   // head = kt (64-wide cols)
            rlv = 1.0f / (lpart[li] + lpart[(size_t)LHALF + li]);
            #pragma unroll
            for (int i = 0; i < 4; ++i) {
                o0[i] = *(const short8*)(Asrc + k0 + i * 8);
                o1[i] = *(const short8*)(Asrc + (size_t)OHALF + k0 + i * 8);
            }
        } else {
            #pragma unroll
            for (int i = 0; i < 4; ++i)
                o0[i] = *(const short8*)(Asrc + k0 + i * 8);
        }
        #pragma unroll
        for (int c = 0; c < 2; ++c)
            nbv[c] = *(const short8*)(Bsrc + k0 + c * 8);
    };
    auto stage = [&]() {
        #pragma unroll
        for (int i = 0; i < 4; ++i) {
            short8 na;
            if constexpr (SPLIT) {
                union { unsigned int u[4]; short8 s8; } pk;
                #pragma unroll
                for (int j = 0; j < 4; ++j) {
                    float f0 = (bf2f((unsigned short)o0[i][2*j])   + bf2f((unsigned short)o1[i][2*j]))   * rlv;
                    float f1 = (bf2f((unsigned short)o0[i][2*j+1]) + bf2f((unsigned short)o1[i][2*j+1])) * rlv;
                    pk.u[j] = bfpk(f0, f1);
                }
                na = pk.s8;
            } else {
                na = o0[i];
            }
            *(short8*)&Al[row2][(cb + i * 8) ^ swzA] = na;
        }
        #pragma unroll
        for (int c = 0; c < 2; ++c)
            *(short8*)&Bl[row4][(cb4 + c * 8) ^ swzB] = nbv[c];
    };

    load_kt(0);
    stage();
    __syncthreads();

    for (int kt = 0; kt < DIM / 64; ++kt) {
        if (kt < DIM / 64 - 1) load_kt(kt + 1);
        #pragma unroll
        for (int kc = 0; kc < 2; ++kc) {
            short8 af[4], bfv[2];
            #pragma unroll
            for (int i = 0; i < 4; ++i) {
                int ra = wm * 64 + i * 16 + l16;
                af[i] = *(const short8*)&Al[ra][(kc * 32 + hi * 8) ^ ((ra & 7) << 3)];
            }
            #pragma unroll
            for (int j = 0; j < 2; ++j) {
                int rb = wn * 32 + j * 16 + l16;
                bfv[j] = *(const short8*)&Bl[rb][(kc * 32 + hi * 8) ^ ((rb & 7) << 3)];
            }
            #pragma unroll
            for (int i = 0; i < 4; ++i)
                #pragma unroll
                for (int j = 0; j < 2; ++j)
                    acc[i][j] = mfma16(af[i], bfv[j], acc[i][j]);
        }
        __syncthreads();
        if (kt < DIM / 64 - 1) {
            stage();
        }
        __syncthreads();
    }

    float bj[2];
    #pragma unroll
    for (int j = 0; j < 2; ++j) bj[j] = bias[n0 + wn * 32 + j * 16 + l16];
    #pragma unroll
    for (int i = 0; i < 4; ++i) {
        #pragma unroll
        for (int j = 0; j < 2; ++j) {
            int n = n0 + wn * 32 + j * 16 + l16;
            #pragma unroll
            for (int r = 0; r < 4; ++r) {
                int m = m0 + wm * 64 + i * 16 + hi * 4 + r;
                Out[(size_t)m * DIM + n] = acc[i][j][r] + bj[j];
            }
        }
    }
}

// ---------------------------------------------------------------------------
extern "C" void kernel_launch(void* const* d_in, const int* in_sizes, int n_in,
                              void* d_out, int out_size, void* d_ws, size_t ws_size,
                              hipStream_t stream) {
    const float* query = (const float*)d_in[0];
    const float* key   = (const float*)d_in[1];
    const float* value = (const float*)d_in[2];
    const float* mask  = (const float*)d_in[3];
    const float* Wq    = (const float*)d_in[4];
    const float* bq    = (const float*)d_in[5];
    const float* Wk    = (const float*)d_in[6];
    const float* bk    = (const float*)d_in[7];
    const float* Wv    = (const float*)d_in[8];
    const float* bv    = (const float*)d_in[9];
    const float* Wo    = (const float*)d_in[10];
    const float* bo    = (const float*)d_in[11];
    float* out = (float*)d_out;

    char* ws = (char*)d_ws;
    unsigned short* Wt    = (unsigned short*)(ws);                            //  8 MB
    unsigned short* Qh    = (unsigned short*)(ws + (size_t)8  * 1024 * 1024); //  8 MB
    unsigned short* Kh    = (unsigned short*)(ws + (size_t)16 * 1024 * 1024); //  8 MB compact+swz
    unsigned short* Vt    = (unsigned short*)(ws + (size_t)24 * 1024 * 1024); //  8 MB compact+swz
    unsigned short* Opart = (unsigned short*)(ws + (size_t)32 * 1024 * 1024); // 16 MB (2 halves)
    float*          lpart = (float*)         (ws + (size_t)48 * 1024 * 1024); // 0.5 MB (written
                                                                              //   AFTER Xbf dead)
    unsigned short* Xbf   = (unsigned short*)(ws + (size_t)32 * 1024 * 1024); // 24 MB, dead
                                                                              //   before attn
    // pos/cnt scratch carved from d_out (16 MB): written by mask_scan at call
    // start, read by pad/proj/attn, then outproj overwrites ALL of d_out.
    int* pos  = (int*)d_out;               // 16 KB
    int* cntb = (int*)d_out + 2 * SEQ;     // 8 B
    const unsigned short* WtO = Wt + (size_t)3 * 1024 * 1024;

    wcvt_kernel<<<dim3(256, 4), 256, 0, stream>>>(Wq, Wk, Wv, Wo, Wt);
    mask_scan_kernel<<<2, 256, 0, stream>>>(mask, pos, cntb);
    pad_kernel<<<32, 256, 0, stream>>>(cntb, Kh, Vt);
    if (ws_size >= (size_t)56 * 1024 * 1024) {
        xcvt_kernel<<<dim3(2048, 3), 256, 0, stream>>>(query, key, value, Xbf);
        proj_kernel<true><<<768, 256, 0, stream>>>(Xbf, query, key, value, Wt,
                                                   bq, bk, bv, pos, Qh, Kh, Vt);
        attn_kernel<true><<<dim3(32, 16, 2), 256, 0, stream>>>(Qh, Kh, Vt, cntb,
                                                               nullptr, Opart, lpart);
        outproj_kernel<true><<<512, 256, 0, stream>>>(Opart, lpart, WtO, bo, out);
    } else {
        proj_kernel<false><<<768, 256, 0, stream>>>(nullptr, query, key, value, Wt,
                                                    bq, bk, bv, pos, Qh, Kh, Vt);
        attn_kernel<false><<<dim3(32, 16, 1), 256, 0, stream>>>(Qh, Kh, Vt, cntb,
                                                                Opart, nullptr, nullptr);
        outproj_kernel<false><<<512, 256, 0, stream>>>(Opart, nullptr, WtO, bo, out);
    }
}

// Round 15
// 126.665 us; speedup vs baseline: 1.0060x; 1.0060x over previous
//
#include <hip/hip_runtime.h>
#include <hip/hip_bf16.h>
#include <stdint.h>

// ---------- types ----------
using short8  = __attribute__((ext_vector_type(8))) short;
using f32x4   = __attribute__((ext_vector_type(4))) float;
using f32x16  = __attribute__((ext_vector_type(16))) float;

__device__ inline unsigned short f2bf(float f) {
    union { float f; unsigned int u; } v; v.f = f;
    unsigned int u = v.u;
    unsigned int r = (u + 0x7FFFu + ((u >> 16) & 1u)) >> 16;   // RNE
    return (unsigned short)r;
}

__device__ inline unsigned short bfu(float f) {
    __hip_bfloat16 h = __float2bfloat16(f);
    union { __hip_bfloat16 h; unsigned short u; } c; c.h = h;
    return c.u;
}

__device__ inline float bf2f(unsigned short u) {
    union { unsigned int u; float f; } v; v.u = (unsigned int)u << 16;
    return v.f;
}

// pack two floats to bf16 pair (compiler fuses to v_cvt_pk_bf16_f32)
__device__ inline unsigned int bfpk(float lo, float hi) {
    return (unsigned int)bfu(lo) | ((unsigned int)bfu(hi) << 16);
}

__device__ inline f32x4 mfma16(short8 a, short8 b, f32x4 c) {
    return __builtin_amdgcn_mfma_f32_16x16x32_bf16(a, b, c, 0, 0, 0);
}
__device__ inline f32x16 mfma32(short8 a, short8 b, f32x16 c) {
    return __builtin_amdgcn_mfma_f32_32x32x16_bf16(a, b, c, 0, 0, 0);
}

// async global->LDS, 16B per lane: LDS dest = wave-uniform base + lane*16
__device__ inline void gld16(const void* g, void* l) {
    __builtin_amdgcn_global_load_lds(
        (const __attribute__((address_space(1))) unsigned int*)g,
        (__attribute__((address_space(3))) unsigned int*)l, 16, 0, 0);
}

// B=2, S=2048, D=1024, H=16, DH=64
#define SEQ 2048
#define DIM 1024
#define NH  16
#define DH  64
#define MROWS 4096      // B*S
#define OHALF 4194304   // B*S*DIM elems per split half
#define LHALF 65536     // B*NH*SEQ elems per split half

// ---------------------------------------------------------------------------
// k0: weight fp32 [k][n] -> bf16 Wt [n][k]  (transpose + convert), 64x64 tiles
// ---------------------------------------------------------------------------
__global__ __launch_bounds__(256) void wcvt_kernel(
    const float* __restrict__ W0, const float* __restrict__ W1,
    const float* __restrict__ W2, const float* __restrict__ W3,
    unsigned short* __restrict__ Wt)
{
    __shared__ unsigned short tile[64][72];
    const float* W = (blockIdx.y == 0) ? W0 : (blockIdx.y == 1) ? W1
                   : (blockIdx.y == 2) ? W2 : W3;
    unsigned short* out = Wt + (size_t)blockIdx.y * DIM * DIM;
    const int t  = threadIdx.x;
    const int tk = blockIdx.x >> 4, tn = blockIdx.x & 15;
    const int k0 = tk * 64, n0 = tn * 64;

    #pragma unroll
    for (int j = 0; j < 4; ++j) {
        int c = t + j * 256;
        int r = c >> 4, c4 = c & 15;
        float4 v = *(const float4*)(W + (size_t)(k0 + r) * DIM + n0 + c4 * 4);
        tile[c4 * 4 + 0][r] = f2bf(v.x);
        tile[c4 * 4 + 1][r] = f2bf(v.y);
        tile[c4 * 4 + 2][r] = f2bf(v.z);
        tile[c4 * 4 + 3][r] = f2bf(v.w);
    }
    __syncthreads();
    #pragma unroll
    for (int j = 0; j < 2; ++j) {
        int c = t + j * 256;
        int r = c >> 3, c8 = c & 7;
        *(short8*)(out + (size_t)(n0 + r) * DIM + k0 + c8 * 8) =
            *(const short8*)&tile[r][c8 * 8];
    }
}

// ---------------------------------------------------------------------------
// k0b: mask scan. pos[b][s] = compact index (-1 if masked); cnt[b] = #live.
//      pos/cnt live in d_out scratch (outproj overwrites d_out last).
// ---------------------------------------------------------------------------
__global__ __launch_bounds__(256) void mask_scan_kernel(
    const float* __restrict__ mask, int* __restrict__ pos, int* __restrict__ cnt)
{
    __shared__ int sums[256];
    const int b = blockIdx.x, t = threadIdx.x;
    const float* m = mask + (size_t)b * SEQ;
    int flags[8], s = 0;
    #pragma unroll
    for (int i = 0; i < 8; ++i) {
        flags[i] = (m[t * 8 + i] == 0.0f) ? 1 : 0;
        s += flags[i];
    }
    sums[t] = s;
    __syncthreads();
    if (t == 0) {
        int acc = 0;
        for (int i = 0; i < 256; ++i) { int x = sums[i]; sums[i] = acc; acc += x; }
        cnt[b] = acc;
    }
    __syncthreads();
    int base = sums[t];
    #pragma unroll
    for (int i = 0; i < 8; ++i) {
        pos[(size_t)b * SEQ + t * 8 + i] = flags[i] ? base : -1;
        base += flags[i];
    }
}

// ---------------------------------------------------------------------------
// k0c: zero the tail pad slots of the last partial 32-tile in Kh / Vt.
// ---------------------------------------------------------------------------
__global__ __launch_bounds__(256) void pad_kernel(
    const int* __restrict__ cnt, unsigned short* __restrict__ Kh,
    unsigned short* __restrict__ Vt)
{
    const int bh = blockIdx.x, b = bh >> 4;
    const int c = cnt[b];
    if ((c & 31) == 0) return;
    const int base = c & ~31;
    const int t = threadIdx.x;
    short8 z = {0, 0, 0, 0, 0, 0, 0, 0};
    *(short8*)(Kh + ((size_t)bh * SEQ + base + (t >> 3)) * DH + (t & 7) * 8) = z;
    *(short8*)(Vt + (size_t)bh * DH * SEQ + (size_t)(t >> 2) * SEQ + base + (t & 3) * 8) = z;
}

// ---------------------------------------------------------------------------
// k1: X fp32 -> bf16 (3 inputs, flat copy). grid (2048, 3)
// ---------------------------------------------------------------------------
__global__ __launch_bounds__(256) void xcvt_kernel(
    const float* __restrict__ Xq, const float* __restrict__ Xk,
    const float* __restrict__ Xv, unsigned short* __restrict__ Xbf)
{
    const int zz = blockIdx.y;
    const float* src = (zz == 0) ? Xq : (zz == 1) ? Xk : Xv;
    size_t i8 = ((size_t)blockIdx.x * 256 + threadIdx.x) * 8;
    float4 v0 = *(const float4*)(src + i8);
    float4 v1 = *(const float4*)(src + i8 + 4);
    union { unsigned int u[4]; short8 s8; } p;
    p.u[0] = bfpk(v0.x, v0.y); p.u[1] = bfpk(v0.z, v0.w);
    p.u[2] = bfpk(v1.x, v1.y); p.u[3] = bfpk(v1.z, v1.w);
    *(short8*)(Xbf + (size_t)zz * MROWS * DIM + i8) = p.s8;
}

// ---------------------------------------------------------------------------
// k2: projection GEMM. BF16A: both operands staged via global_load_lds DMA
//     (linear LDS dest + source-address pre-swizzle; XOR ds_read unchanged).
//     z=0 -> Qh (scaled 0.125*log2e); z=1 -> Kh COMPACTED; z=2 -> Vt
//     COMPACTED transposed.
// ---------------------------------------------------------------------------
template<bool BF16A>
__global__ __launch_bounds__(256, 3) void proj_kernel(
    const unsigned short* __restrict__ Xbf,
    const float* __restrict__ Xq, const float* __restrict__ Xk, const float* __restrict__ Xv,
    const unsigned short* __restrict__ Wt,
    const float* __restrict__ bq, const float* __restrict__ bk, const float* __restrict__ bv,
    const int* __restrict__ pos,
    unsigned short* __restrict__ Qh, unsigned short* __restrict__ Kh,
    unsigned short* __restrict__ Vt)
{
    __shared__ unsigned short Al[128][64];
    __shared__ unsigned short Bl[128][64];

    const int bid = blockIdx.x;
    const int z = bid >> 8;
    const int p = bid & 255;
    const int qq = p >> 3;
    const int mb = (p & 7) | ((qq & 3) << 3);   // 0..31
    const int nb = qq >> 2;                     // 0..7
    const int m0 = mb * 128, n0 = nb * 128;

    const unsigned short* W = Wt + (size_t)z * DIM * DIM;
    const float* bias = (z == 0) ? bq : (z == 1) ? bk : bv;

    const int t = threadIdx.x, lane = t & 63, w = t >> 6;
    const int l16 = lane & 15, hi = lane >> 4;
    const int wm = w >> 1, wn = w & 1;

    f32x4 zero4 = {0.f, 0.f, 0.f, 0.f};
    f32x4 acc[4][4];
    #pragma unroll
    for (int i = 0; i < 4; ++i)
        #pragma unroll
        for (int j = 0; j < 4; ++j) acc[i][j] = zero4;

    if constexpr (BF16A) {
        const unsigned short* Abase = Xbf + (size_t)z * MROWS * DIM + (size_t)m0 * DIM;
        const unsigned short* Bbase = W + (size_t)n0 * DIM;
        const unsigned short* asrc[4];
        const unsigned short* bsrc[4];
        unsigned short* adst[4];
        unsigned short* bdst[4];
        #pragma unroll
        for (int pass = 0; pass < 4; ++pass) {
            int c = pass * 256 + t;
            int row = c >> 3;
            int colg = (((c & 7) ^ (row & 7)) * 8);
            asrc[pass] = Abase + (size_t)row * DIM + colg;
            bsrc[pass] = Bbase + (size_t)row * DIM + colg;
            adst[pass] = &Al[0][0] + c * 8;
            bdst[pass] = &Bl[0][0] + c * 8;
        }
        for (int kt = 0; kt < DIM / 64; ++kt) {
            const int k0 = kt * 64;
            #pragma unroll
            for (int pass = 0; pass < 4; ++pass) {
                gld16(asrc[pass] + k0, adst[pass]);
                gld16(bsrc[pass] + k0, bdst[pass]);
            }
            asm volatile("s_waitcnt vmcnt(0)" ::: "memory");
            __syncthreads();
            #pragma unroll
            for (int kc = 0; kc < 2; ++kc) {
                short8 af[4], bfv[4];
                #pragma unroll
                for (int i = 0; i < 4; ++i) {
                    int ra = wm * 64 + i * 16 + l16;
                    af[i] = *(const short8*)&Al[ra][(kc * 32 + hi * 8) ^ ((ra & 7) << 3)];
                }
                #pragma unroll
                for (int j = 0; j < 4; ++j) {
                    int rb = wn * 64 + j * 16 + l16;
                    bfv[j] = *(const short8*)&Bl[rb][(kc * 32 + hi * 8) ^ ((rb & 7) << 3)];
                }
                #pragma unroll
                for (int i = 0; i < 4; ++i)
                    #pragma unroll
                    for (int j = 0; j < 4; ++j)
                        acc[i][j] = mfma16(af[i], bfv[j], acc[i][j]);
            }
            __syncthreads();
        }
    } else {
        const int row2 = t >> 1, part = t & 1;
        const int swz = (row2 & 7) << 3;
        const int cb = part * 32;
        const float* X = (z == 0) ? Xq : (z == 1) ? Xk : Xv;
        const float* Asrc_f = X + (size_t)(m0 + row2) * DIM + cb;
        const unsigned short* Bsrc = W + (size_t)(n0 + row2) * DIM + cb;

        short8 na[4], nbv[4];
        auto ldA = [&](int k0, int i) {
            float4 f0 = *(const float4*)(Asrc_f + k0 + i * 8);
            float4 f1 = *(const float4*)(Asrc_f + k0 + i * 8 + 4);
            union { unsigned int u[4]; short8 s8; } pk;
            pk.u[0] = bfpk(f0.x, f0.y); pk.u[1] = bfpk(f0.z, f0.w);
            pk.u[2] = bfpk(f1.x, f1.y); pk.u[3] = bfpk(f1.z, f1.w);
            return pk.s8;
        };
        #pragma unroll
        for (int i = 0; i < 4; ++i) {
            na[i]  = ldA(0, i);
            nbv[i] = *(const short8*)(Bsrc + i * 8);
        }
        #pragma unroll
        for (int i = 0; i < 4; ++i) {
            *(short8*)&Al[row2][(cb + i * 8) ^ swz] = na[i];
            *(short8*)&Bl[row2][(cb + i * 8) ^ swz] = nbv[i];
        }
        __syncthreads();
        for (int kt = 0; kt < DIM / 64; ++kt) {
            if (kt < DIM / 64 - 1) {
                const int k0n = (kt + 1) * 64;
                #pragma unroll
                for (int i = 0; i < 4; ++i) {
                    na[i]  = ldA(k0n, i);
                    nbv[i] = *(const short8*)(Bsrc + k0n + i * 8);
                }
            }
            #pragma unroll
            for (int kc = 0; kc < 2; ++kc) {
                short8 af[4], bfv[4];
                #pragma unroll
                for (int i = 0; i < 4; ++i) {
                    int ra = wm * 64 + i * 16 + l16;
                    af[i] = *(const short8*)&Al[ra][(kc * 32 + hi * 8) ^ ((ra & 7) << 3)];
                }
                #pragma unroll
                for (int j = 0; j < 4; ++j) {
                    int rb = wn * 64 + j * 16 + l16;
                    bfv[j] = *(const short8*)&Bl[rb][(kc * 32 + hi * 8) ^ ((rb & 7) << 3)];
                }
                #pragma unroll
                for (int i = 0; i < 4; ++i)
                    #pragma unroll
                    for (int j = 0; j < 4; ++j)
                        acc[i][j] = mfma16(af[i], bfv[j], acc[i][j]);
            }
            __syncthreads();
            if (kt < DIM / 64 - 1) {
                #pragma unroll
                for (int i = 0; i < 4; ++i) {
                    *(short8*)&Al[row2][(cb + i * 8) ^ swz] = na[i];
                    *(short8*)&Bl[row2][(cb + i * 8) ^ swz] = nbv[i];
                }
            }
            __syncthreads();
        }
    }

    float bj[4];
    #pragma unroll
    for (int j = 0; j < 4; ++j) bj[j] = bias[n0 + wn * 64 + j * 16 + l16];

    if (z == 2) {
        #pragma unroll
        for (int i = 0; i < 4; ++i) {
            int mrow0 = m0 + wm * 64 + i * 16 + hi * 4;
            int bb = mrow0 >> 11, s = mrow0 & (SEQ - 1);
            #pragma unroll
            for (int r = 0; r < 4; ++r) {
                int p_ = pos[(size_t)bb * SEQ + s + r];
                if (p_ < 0) continue;
                #pragma unroll
                for (int j = 0; j < 4; ++j) {
                    int n = n0 + wn * 64 + j * 16 + l16;
                    int dn = n & 63, hh = n >> 6;
                    int scol = (p_ & ~31) | ((((p_ >> 3) & 3) ^ ((dn >> 1) & 3)) << 3)
                             | (p_ & 7);
                    Vt[((size_t)(bb * NH + hh) * DH + dn) * SEQ + scol] =
                        bfu(acc[i][j][r] + bj[j]);
                }
            }
        }
    } else if (z == 1) {
        #pragma unroll
        for (int i = 0; i < 4; ++i) {
            int mrow0 = m0 + wm * 64 + i * 16 + hi * 4;
            int bb = mrow0 >> 11, s = mrow0 & (SEQ - 1);
            #pragma unroll
            for (int r = 0; r < 4; ++r) {
                int p_ = pos[(size_t)bb * SEQ + s + r];
                if (p_ < 0) continue;
                #pragma unroll
                for (int j = 0; j < 4; ++j) {
                    int n = n0 + wn * 64 + j * 16 + l16;
                    int hh = n >> 6, d = n & 63;
                    int dsw = (d & 7) | ((((d >> 3) ^ (p_ & 7)) & 7) << 3);
                    Kh[((size_t)(bb * NH + hh) * SEQ + p_) * DH + dsw] =
                        bfu(acc[i][j][r] + bj[j]);
                }
            }
        }
    } else {
        const float sc = 0.125f * 1.4426950408889634f;   // fold 1/sqrt(DH)*log2e
        #pragma unroll
        for (int i = 0; i < 4; ++i) {
            #pragma unroll
            for (int j = 0; j < 4; ++j) {
                int n = n0 + wn * 64 + j * 16 + l16;
                int hh = n >> 6, d = n & 63;
                #pragma unroll
                for (int r = 0; r < 4; ++r) {
                    int mrow = m0 + wm * 64 + i * 16 + hi * 4 + r;
                    int bb = mrow >> 11, s = mrow & (SEQ - 1);
                    Qh[((size_t)(bb * NH + hh) * SEQ + s) * DH + d] =
                        bfu((acc[i][j][r] + bj[j]) * sc);
                }
            }
        }
    }
}

// ---------------------------------------------------------------------------
// k3: flash attention over COMPACTED K/V (cnt[b] live columns, 32-padded).
//     8 waves x 32 q (QBLK=256), KVBLK=32, LDS 16KB. Waves 0-3 DMA K,
//     4-7 DMA V. SPLIT: halves of ceil(cnt/32) tiles; partials are pure
//     sums (max-free softmax), combined in outproj.
//     (R14 falsified smaller blocks: 8-wave overlap beats block count.)
// ---------------------------------------------------------------------------
template<bool SPLIT>
__global__ __launch_bounds__(512) void attn_kernel(
    const unsigned short* __restrict__ Qh,
    const unsigned short* __restrict__ Kh,
    const unsigned short* __restrict__ Vtp,
    const int* __restrict__ cntbuf,
    unsigned short* __restrict__ AO,
    unsigned short* __restrict__ Opart,
    float* __restrict__ lpart)
{
    __shared__ unsigned short Kl[2][32 * 64];    // [s(32)][d(64)]
    __shared__ unsigned short Vl[2][64 * 32];    // [d(64)][s(32)]

    const int t = threadIdx.x, lane = t & 63, w = t >> 6;   // w 0..7
    const int l31 = lane & 31, h32 = lane >> 5;
    const int bh = blockIdx.x, b = bh >> 4, h = bh & (NH - 1);
    const int q0 = blockIdx.y * 256 + w * 32;
    const int half = SPLIT ? blockIdx.z : 0;

    const int cnt = cntbuf[b];
    const int NTt = (cnt + 31) >> 5;             // total tiles
    const int NTh0 = (NTt + 1) >> 1;
    const int t0   = (SPLIT && half) ? NTh0 : 0;
    const int myNT = SPLIT ? (half ? NTt - NTh0 : NTh0) : NTt;

    const unsigned short* Q = Qh + (size_t)bh * SEQ * DH;
    const unsigned short* K = Kh + (size_t)bh * SEQ * DH;
    const unsigned short* V = Vtp + (size_t)bh * DH * SEQ;

    const int cs = (w & 3) * 64 + lane;
    const bool isK = (w < 4);

    short8 qf[4];
    #pragma unroll
    for (int ds = 0; ds < 4; ++ds)
        qf[ds] = *(const short8*)(Q + (size_t)(q0 + l31) * DH + ds * 16 + h32 * 8);

    f32x16 o[2], ol;
    #pragma unroll
    for (int r = 0; r < 16; ++r) { o[0][r] = 0.f; o[1][r] = 0.f; ol[r] = 0.f; }

    {
        const int kb0 = t0 * 32;
        if (isK) gld16(K + (size_t)(kb0 + (cs >> 3)) * DH + (cs & 7) * 8, &Kl[0][cs * 8]);
        else     gld16(V + (size_t)(cs >> 2) * SEQ + kb0 + (cs & 3) * 8,  &Vl[0][cs * 8]);
    }
    asm volatile("s_waitcnt vmcnt(0)" ::: "memory");
    __syncthreads();

    for (int it = 0; it < myNT; ++it) {
        const int tile = t0 + it;
        const int cur = it & 1;
        const int kb = tile * 32;
        const int nt_ = (it + 1 < myNT) ? (tile + 1) : t0;
        const int nkb = nt_ * 32;

        if (isK) gld16(K + (size_t)(nkb + (cs >> 3)) * DH + (cs & 7) * 8, &Kl[cur ^ 1][cs * 8]);
        else     gld16(V + (size_t)(cs >> 2) * SEQ + nkb + (cs & 3) * 8,  &Vl[cur ^ 1][cs * 8]);

        short8 wf[2];
        if (kb + 32 <= cnt) {
            #pragma unroll
            for (int ss = 0; ss < 2; ++ss)
                #pragma unroll
                for (int e = 0; e < 8; ++e) wf[ss][e] = (short)0x3F80;
        } else {
            #pragma unroll
            for (int ss = 0; ss < 2; ++ss)
                #pragma unroll
                for (int e = 0; e < 8; ++e)
                    wf[ss][e] = (short)((kb + ss * 16 + h32 * 8 + e < cnt) ? 0x3F80 : 0);
        }

        f32x16 st;
        #pragma unroll
        for (int r = 0; r < 16; ++r) st[r] = 0.f;
        __builtin_amdgcn_s_setprio(1);
        #pragma unroll
        for (int ds = 0; ds < 4; ++ds) {
            short8 kfr = *(const short8*)
                &Kl[cur][l31 * 64 + (((ds * 2 + h32) ^ (l31 & 7)) * 8)];
            st = mfma32(kfr, qf[ds], st);
        }
        __builtin_amdgcn_s_setprio(0);

        #pragma unroll
        for (int r = 0; r < 16; ++r) st[r] = exp2f(st[r]);

        short8 pa[2];
        #pragma unroll
        for (int ss = 0; ss < 2; ++ss) {
            const int rb = ss * 8;
            unsigned int a0 = bfpk(st[rb + 0], st[rb + 1]);
            unsigned int a1 = bfpk(st[rb + 2], st[rb + 3]);
            unsigned int b0 = bfpk(st[rb + 4], st[rb + 5]);
            unsigned int b1 = bfpk(st[rb + 6], st[rb + 7]);
            asm volatile("v_permlane32_swap_b32 %0, %1" : "+v"(a0), "+v"(b0));
            asm volatile("v_permlane32_swap_b32 %0, %1" : "+v"(a1), "+v"(b1));
            union { unsigned int u[4]; short8 s8; } up;
            up.u[0] = a0; up.u[1] = a1; up.u[2] = b0; up.u[3] = b1;
            pa[ss] = up.s8;
        }

        __builtin_amdgcn_s_setprio(1);
        #pragma unroll
        for (int ss = 0; ss < 2; ++ss) {
            #pragma unroll
            for (int dblk = 0; dblk < 2; ++dblk) {
                int vrow = dblk * 32 + l31;
                short8 vfr = *(const short8*)
                    &Vl[cur][vrow * 32 + (((ss * 2 + h32) ^ ((l31 >> 1) & 3)) * 8)];
                o[dblk] = mfma32(pa[ss], vfr, o[dblk]);
            }
            ol = mfma32(pa[ss], wf[ss], ol);
        }
        __builtin_amdgcn_s_setprio(0);

        asm volatile("s_waitcnt vmcnt(0)" ::: "memory");
        __syncthreads();
    }
    asm volatile("s_waitcnt vmcnt(0)" ::: "memory");   // covers myNT==0 prologue DMA

    if constexpr (SPLIT) {
        #pragma unroll
        for (int dblk = 0; dblk < 2; ++dblk) {
            #pragma unroll
            for (int r = 0; r < 16; ++r) {
                int q = (r & 3) + 8 * (r >> 2) + 4 * h32;
                Opart[(size_t)half * OHALF + (size_t)(b * SEQ + q0 + q) * DIM
                      + h * DH + dblk * 32 + l31] = bfu(o[dblk][r]);
            }
        }
        if (l31 == 0) {
            #pragma unroll
            for (int r = 0; r < 16; ++r) {
                int q = (r & 3) + 8 * (r >> 2) + 4 * h32;
                lpart[(size_t)half * LHALF + bh * SEQ + q0 + q] = ol[r];
            }
        }
    } else {
        float rcl[16];
        #pragma unroll
        for (int r = 0; r < 16; ++r) rcl[r] = 1.0f / ol[r];
        #pragma unroll
        for (int dblk = 0; dblk < 2; ++dblk) {
            #pragma unroll
            for (int r = 0; r < 16; ++r) {
                int q = (r & 3) + 8 * (r >> 2) + 4 * h32;
                AO[(size_t)(b * SEQ + q0 + q) * DIM + h * DH + dblk * 32 + l31] =
                    bfu(o[dblk][r] * rcl[r]);
            }
        }
    }
}

// ---------------------------------------------------------------------------
// k4: output GEMM, 128x64 tiles -> 512 blocks. SPLIT fuses the half-combine
//     ((O0+O1)/(l0+l1)) into A-staging. B staged via global_load_lds DMA,
//     double-buffered (issue at loop top; other buffer idle per ping-pong
//     barrier; vmcnt(0) before the stage-barrier).
// ---------------------------------------------------------------------------
template<bool SPLIT>
__global__ __launch_bounds__(256, 3) void outproj_kernel(
    const unsigned short* __restrict__ Op0, const float* __restrict__ lpart,
    const unsigned short* __restrict__ W,
    const float* __restrict__ bias, float* __restrict__ Out)
{
    __shared__ unsigned short Al[128][64];
    __shared__ unsigned short Bl[2][64 * 64];

    const int p = blockIdx.x;                   // 0..511
    const int qq = p >> 3;                      // 0..63
    const int mb = (p & 7) | ((qq & 3) << 3);   // 0..31 ; p%8 = mb%8 (XCD)
    const int nb = qq >> 2;                     // 0..15
    const int m0 = mb * 128, n0 = nb * 64;

    const int t = threadIdx.x, lane = t & 63, w = t >> 6;
    const int l16 = lane & 15, hi = lane >> 4;
    const int wm = w >> 1, wn = w & 1;
    const int row2 = t >> 1, part = t & 1;
    const int swzA = (row2 & 7) << 3;
    const int cb = part * 32;

    // B DMA geometry: chunk c = pass*256+t (pass<2); row=c>>3, granule XOR
    const unsigned short* bsrc[2];
    int bdst[2];
    #pragma unroll
    for (int pass = 0; pass < 2; ++pass) {
        int c = pass * 256 + t;
        int row = c >> 3;
        int colg = ((c & 7) ^ (row & 7)) * 8;
        bsrc[pass] = W + (size_t)(n0 + row) * DIM + colg;
        bdst[pass] = c * 8;
    }

    const int arow = m0 + row2;
    const int bb = arow >> 11, sA = arow & (SEQ - 1);
    const unsigned short* Asrc = Op0 + (size_t)arow * DIM + cb;

    f32x4 zero4 = {0.f, 0.f, 0.f, 0.f};
    f32x4 acc[4][2];
    #pragma unroll
    for (int i = 0; i < 4; ++i) { acc[i][0] = zero4; acc[i][1] = zero4; }

    short8 o0[4], o1[4];
    float rlv = 0.f;

    auto load_kt = [&](int kt) {
        const int k0 = kt * 64;
        if constexpr (SPLIT) {
            size_t li = (size_t)(bb * NH + kt) * SEQ + sA;   // head = kt (64-wide cols)
            rlv = 1.0f / (lpart[li] + lpart[(size_t)LHALF + li]);
            #pragma unroll
            for (int i = 0; i < 4; ++i) {
                o0[i] = *(const short8*)(Asrc + k0 + i * 8);
                o1[i] = *(const short8*)(Asrc + (size_t)OHALF + k0 + i * 8);
            }
        } else {
            #pragma unroll
            for (int i = 0; i < 4; ++i)
                o0[i] = *(const short8*)(Asrc + k0 + i * 8);
        }
    };
    auto stageA = [&]() {
        #pragma unroll
        for (int i = 0; i < 4; ++i) {
            short8 na;
            if constexpr (SPLIT) {
                union { unsigned int u[4]; short8 s8; } pk;
                #pragma unroll
                for (int j = 0; j < 4; ++j) {
                    float f0 = (bf2f((unsigned short)o0[i][2*j])   + bf2f((unsigned short)o1[i][2*j]))   * rlv;
                    float f1 = (bf2f((unsigned short)o0[i][2*j+1]) + bf2f((unsigned short)o1[i][2*j+1])) * rlv;
                    pk.u[j] = bfpk(f0, f1);
                }
                na = pk.s8;
            } else {
                na = o0[i];
            }
            *(short8*)&Al[row2][(cb + i * 8) ^ swzA] = na;
        }
    };

    // prologue: B DMA kt0 -> Bl[0]; A kt0 regs -> stage
    gld16(bsrc[0], &Bl[0][bdst[0]]);
    gld16(bsrc[1], &Bl[0][bdst[1]]);
    load_kt(0);
    stageA();
    asm volatile("s_waitcnt vmcnt(0)" ::: "memory");
    __syncthreads();

    for (int kt = 0; kt < DIM / 64; ++kt) {
        const int cur = kt & 1;
        if (kt < DIM / 64 - 1) {
            const int k0n = (kt + 1) * 64;
            gld16(bsrc[0] + k0n, &Bl[cur ^ 1][bdst[0]]);
            gld16(bsrc[1] + k0n, &Bl[cur ^ 1][bdst[1]]);
            load_kt(kt + 1);
        }
        #pragma unroll
        for (int kc = 0; kc < 2; ++kc) {
            short8 af[4], bfv[2];
            #pragma unroll
            for (int i = 0; i < 4; ++i) {
                int ra = wm * 64 + i * 16 + l16;
                af[i] = *(const short8*)&Al[ra][(kc * 32 + hi * 8) ^ ((ra & 7) << 3)];
            }
            #pragma unroll
            for (int j = 0; j < 2; ++j) {
                int rb = wn * 32 + j * 16 + l16;
                bfv[j] = *(const short8*)
                    &Bl[cur][rb * 64 + ((kc * 32 + hi * 8) ^ ((rb & 7) << 3))];
            }
            #pragma unroll
            for (int i = 0; i < 4; ++i)
                #pragma unroll
                for (int j = 0; j < 2; ++j)
                    acc[i][j] = mfma16(af[i], bfv[j], acc[i][j]);
        }
        __syncthreads();
        if (kt < DIM / 64 - 1) {
            stageA();
        }
        asm volatile("s_waitcnt vmcnt(0)" ::: "memory");
        __syncthreads();
    }

    float bj[2];
    #pragma unroll
    for (int j = 0; j < 2; ++j) bj[j] = bias[n0 + wn * 32 + j * 16 + l16];
    #pragma unroll
    for (int i = 0; i < 4; ++i) {
        #pragma unroll
        for (int j = 0; j < 2; ++j) {
            int n = n0 + wn * 32 + j * 16 + l16;
            #pragma unroll
            for (int r = 0; r < 4; ++r) {
                int m = m0 + wm * 64 + i * 16 + hi * 4 + r;
                Out[(size_t)m * DIM + n] = acc[i][j][r] + bj[j];
            }
        }
    }
}

// ---------------------------------------------------------------------------
extern "C" void kernel_launch(void* const* d_in, const int* in_sizes, int n_in,
                              void* d_out, int out_size, void* d_ws, size_t ws_size,
                              hipStream_t stream) {
    const float* query = (const float*)d_in[0];
    const float* key   = (const float*)d_in[1];
    const float* value = (const float*)d_in[2];
    const float* mask  = (const float*)d_in[3];
    const float* Wq    = (const float*)d_in[4];
    const float* bq    = (const float*)d_in[5];
    const float* Wk    = (const float*)d_in[6];
    const float* bk    = (const float*)d_in[7];
    const float* Wv    = (const float*)d_in[8];
    const float* bv    = (const float*)d_in[9];
    const float* Wo    = (const float*)d_in[10];
    const float* bo    = (const float*)d_in[11];
    float* out = (float*)d_out;

    char* ws = (char*)d_ws;
    unsigned short* Wt    = (unsigned short*)(ws);                            //  8 MB
    unsigned short* Qh    = (unsigned short*)(ws + (size_t)8  * 1024 * 1024); //  8 MB
    unsigned short* Kh    = (unsigned short*)(ws + (size_t)16 * 1024 * 1024); //  8 MB compact+swz
    unsigned short* Vt    = (unsigned short*)(ws + (size_t)24 * 1024 * 1024); //  8 MB compact+swz
    unsigned short* Opart = (unsigned short*)(ws + (size_t)32 * 1024 * 1024); // 16 MB (2 halves)
    float*          lpart = (float*)         (ws + (size_t)48 * 1024 * 1024); // 0.5 MB (written
                                                                              //   AFTER Xbf dead)
    unsigned short* Xbf   = (unsigned short*)(ws + (size_t)32 * 1024 * 1024); // 24 MB, dead
                                                                              //   before attn
    // pos/cnt scratch carved from d_out (16 MB): written by mask_scan at call
    // start, read by pad/proj/attn, then outproj overwrites ALL of d_out.
    int* pos  = (int*)d_out;               // 16 KB
    int* cntb = (int*)d_out + 2 * SEQ;     // 8 B
    const unsigned short* WtO = Wt + (size_t)3 * 1024 * 1024;

    wcvt_kernel<<<dim3(256, 4), 256, 0, stream>>>(Wq, Wk, Wv, Wo, Wt);
    mask_scan_kernel<<<2, 256, 0, stream>>>(mask, pos, cntb);
    pad_kernel<<<32, 256, 0, stream>>>(cntb, Kh, Vt);
    if (ws_size >= (size_t)56 * 1024 * 1024) {
        xcvt_kernel<<<dim3(2048, 3), 256, 0, stream>>>(query, key, value, Xbf);
        proj_kernel<true><<<768, 256, 0, stream>>>(Xbf, query, key, value, Wt,
                                                   bq, bk, bv, pos, Qh, Kh, Vt);
        attn_kernel<true><<<dim3(32, 8, 2), 512, 0, stream>>>(Qh, Kh, Vt, cntb,
                                                              nullptr, Opart, lpart);
        outproj_kernel<true><<<512, 256, 0, stream>>>(Opart, lpart, WtO, bo, out);
    } else {
        proj_kernel<false><<<768, 256, 0, stream>>>(nullptr, query, key, value, Wt,
                                                    bq, bk, bv, pos, Qh, Kh, Vt);
        attn_kernel<false><<<dim3(32, 8, 1), 512, 0, stream>>>(Qh, Kh, Vt, cntb,
                                                               Opart, nullptr, nullptr);
        outproj_kernel<false><<<512, 256, 0, stream>>>(Opart, nullptr, WtO, bo, out);
    }
}

// Round 16
// 123.012 us; speedup vs baseline: 1.0359x; 1.0297x over previous
//
#include <hip/hip_runtime.h>
#include <hip/hip_bf16.h>
#include <stdint.h>

// ---------- types ----------
using short8  = __attribute__((ext_vector_type(8))) short;
using f32x4   = __attribute__((ext_vector_type(4))) float;
using f32x16  = __attribute__((ext_vector_type(16))) float;

__device__ inline unsigned short f2bf(float f) {
    union { float f; unsigned int u; } v; v.f = f;
    unsigned int u = v.u;
    unsigned int r = (u + 0x7FFFu + ((u >> 16) & 1u)) >> 16;   // RNE
    return (unsigned short)r;
}

__device__ inline unsigned short bfu(float f) {
    __hip_bfloat16 h = __float2bfloat16(f);
    union { __hip_bfloat16 h; unsigned short u; } c; c.h = h;
    return c.u;
}

__device__ inline float bf2f(unsigned short u) {
    union { unsigned int u; float f; } v; v.u = (unsigned int)u << 16;
    return v.f;
}

// pack two floats to bf16 pair (compiler fuses to v_cvt_pk_bf16_f32)
__device__ inline unsigned int bfpk(float lo, float hi) {
    return (unsigned int)bfu(lo) | ((unsigned int)bfu(hi) << 16);
}

__device__ inline f32x4 mfma16(short8 a, short8 b, f32x4 c) {
    return __builtin_amdgcn_mfma_f32_16x16x32_bf16(a, b, c, 0, 0, 0);
}
__device__ inline f32x16 mfma32(short8 a, short8 b, f32x16 c) {
    return __builtin_amdgcn_mfma_f32_32x32x16_bf16(a, b, c, 0, 0, 0);
}

// async global->LDS, 16B per lane: LDS dest = wave-uniform base + lane*16
__device__ inline void gld16(const void* g, void* l) {
    __builtin_amdgcn_global_load_lds(
        (const __attribute__((address_space(1))) unsigned int*)g,
        (__attribute__((address_space(3))) unsigned int*)l, 16, 0, 0);
}

// B=2, S=2048, D=1024, H=16, DH=64
#define SEQ 2048
#define DIM 1024
#define NH  16
#define DH  64
#define MROWS 4096      // B*S
#define OHALF 4194304   // B*S*DIM elems per split half
#define LHALF 65536     // B*NH*SEQ elems per split half

// ---------------------------------------------------------------------------
// k0: weight fp32 [k][n] -> bf16 Wt [n][k]  (transpose + convert), 64x64 tiles
// ---------------------------------------------------------------------------
__global__ __launch_bounds__(256) void wcvt_kernel(
    const float* __restrict__ W0, const float* __restrict__ W1,
    const float* __restrict__ W2, const float* __restrict__ W3,
    unsigned short* __restrict__ Wt)
{
    __shared__ unsigned short tile[64][72];
    const float* W = (blockIdx.y == 0) ? W0 : (blockIdx.y == 1) ? W1
                   : (blockIdx.y == 2) ? W2 : W3;
    unsigned short* out = Wt + (size_t)blockIdx.y * DIM * DIM;
    const int t  = threadIdx.x;
    const int tk = blockIdx.x >> 4, tn = blockIdx.x & 15;
    const int k0 = tk * 64, n0 = tn * 64;

    #pragma unroll
    for (int j = 0; j < 4; ++j) {
        int c = t + j * 256;
        int r = c >> 4, c4 = c & 15;
        float4 v = *(const float4*)(W + (size_t)(k0 + r) * DIM + n0 + c4 * 4);
        tile[c4 * 4 + 0][r] = f2bf(v.x);
        tile[c4 * 4 + 1][r] = f2bf(v.y);
        tile[c4 * 4 + 2][r] = f2bf(v.z);
        tile[c4 * 4 + 3][r] = f2bf(v.w);
    }
    __syncthreads();
    #pragma unroll
    for (int j = 0; j < 2; ++j) {
        int c = t + j * 256;
        int r = c >> 3, c8 = c & 7;
        *(short8*)(out + (size_t)(n0 + r) * DIM + k0 + c8 * 8) =
            *(const short8*)&tile[r][c8 * 8];
    }
}

// ---------------------------------------------------------------------------
// k0b: mask scan. pos[b][s] = compact index (-1 if masked); cnt[b] = #live.
//      pos/cnt live in d_out scratch (outproj overwrites d_out last).
// ---------------------------------------------------------------------------
__global__ __launch_bounds__(256) void mask_scan_kernel(
    const float* __restrict__ mask, int* __restrict__ pos, int* __restrict__ cnt)
{
    __shared__ int sums[256];
    const int b = blockIdx.x, t = threadIdx.x;
    const float* m = mask + (size_t)b * SEQ;
    int flags[8], s = 0;
    #pragma unroll
    for (int i = 0; i < 8; ++i) {
        flags[i] = (m[t * 8 + i] == 0.0f) ? 1 : 0;
        s += flags[i];
    }
    sums[t] = s;
    __syncthreads();
    if (t == 0) {
        int acc = 0;
        for (int i = 0; i < 256; ++i) { int x = sums[i]; sums[i] = acc; acc += x; }
        cnt[b] = acc;
    }
    __syncthreads();
    int base = sums[t];
    #pragma unroll
    for (int i = 0; i < 8; ++i) {
        pos[(size_t)b * SEQ + t * 8 + i] = flags[i] ? base : -1;
        base += flags[i];
    }
}

// ---------------------------------------------------------------------------
// k0c: zero the tail pad slots of the last partial 32-tile in Kh / Vt.
// ---------------------------------------------------------------------------
__global__ __launch_bounds__(256) void pad_kernel(
    const int* __restrict__ cnt, unsigned short* __restrict__ Kh,
    unsigned short* __restrict__ Vt)
{
    const int bh = blockIdx.x, b = bh >> 4;
    const int c = cnt[b];
    if ((c & 31) == 0) return;
    const int base = c & ~31;
    const int t = threadIdx.x;
    short8 z = {0, 0, 0, 0, 0, 0, 0, 0};
    *(short8*)(Kh + ((size_t)bh * SEQ + base + (t >> 3)) * DH + (t & 7) * 8) = z;
    *(short8*)(Vt + (size_t)bh * DH * SEQ + (size_t)(t >> 2) * SEQ + base + (t & 3) * 8) = z;
}

// ---------------------------------------------------------------------------
// k1: X fp32 -> bf16 (3 inputs, flat copy). grid (2048, 3)
// ---------------------------------------------------------------------------
__global__ __launch_bounds__(256) void xcvt_kernel(
    const float* __restrict__ Xq, const float* __restrict__ Xk,
    const float* __restrict__ Xv, unsigned short* __restrict__ Xbf)
{
    const int zz = blockIdx.y;
    const float* src = (zz == 0) ? Xq : (zz == 1) ? Xk : Xv;
    size_t i8 = ((size_t)blockIdx.x * 256 + threadIdx.x) * 8;
    float4 v0 = *(const float4*)(src + i8);
    float4 v1 = *(const float4*)(src + i8 + 4);
    union { unsigned int u[4]; short8 s8; } p;
    p.u[0] = bfpk(v0.x, v0.y); p.u[1] = bfpk(v0.z, v0.w);
    p.u[2] = bfpk(v1.x, v1.y); p.u[3] = bfpk(v1.z, v1.w);
    *(short8*)(Xbf + (size_t)zz * MROWS * DIM + i8) = p.s8;
}

// ---------------------------------------------------------------------------
// k2: projection GEMM. BF16A: both operands staged via global_load_lds DMA
//     (linear LDS dest + source-address pre-swizzle; XOR ds_read unchanged).
//     z=0 -> Qh (scaled 0.125*log2e); z=1 -> Kh COMPACTED; z=2 -> Vt
//     COMPACTED transposed.
// ---------------------------------------------------------------------------
template<bool BF16A>
__global__ __launch_bounds__(256, 3) void proj_kernel(
    const unsigned short* __restrict__ Xbf,
    const float* __restrict__ Xq, const float* __restrict__ Xk, const float* __restrict__ Xv,
    const unsigned short* __restrict__ Wt,
    const float* __restrict__ bq, const float* __restrict__ bk, const float* __restrict__ bv,
    const int* __restrict__ pos,
    unsigned short* __restrict__ Qh, unsigned short* __restrict__ Kh,
    unsigned short* __restrict__ Vt)
{
    __shared__ unsigned short Al[128][64];
    __shared__ unsigned short Bl[128][64];

    const int bid = blockIdx.x;
    const int z = bid >> 8;
    const int p = bid & 255;
    const int qq = p >> 3;
    const int mb = (p & 7) | ((qq & 3) << 3);   // 0..31
    const int nb = qq >> 2;                     // 0..7
    const int m0 = mb * 128, n0 = nb * 128;

    const unsigned short* W = Wt + (size_t)z * DIM * DIM;
    const float* bias = (z == 0) ? bq : (z == 1) ? bk : bv;

    const int t = threadIdx.x, lane = t & 63, w = t >> 6;
    const int l16 = lane & 15, hi = lane >> 4;
    const int wm = w >> 1, wn = w & 1;

    f32x4 zero4 = {0.f, 0.f, 0.f, 0.f};
    f32x4 acc[4][4];
    #pragma unroll
    for (int i = 0; i < 4; ++i)
        #pragma unroll
        for (int j = 0; j < 4; ++j) acc[i][j] = zero4;

    if constexpr (BF16A) {
        const unsigned short* Abase = Xbf + (size_t)z * MROWS * DIM + (size_t)m0 * DIM;
        const unsigned short* Bbase = W + (size_t)n0 * DIM;
        const unsigned short* asrc[4];
        const unsigned short* bsrc[4];
        unsigned short* adst[4];
        unsigned short* bdst[4];
        #pragma unroll
        for (int pass = 0; pass < 4; ++pass) {
            int c = pass * 256 + t;
            int row = c >> 3;
            int colg = (((c & 7) ^ (row & 7)) * 8);
            asrc[pass] = Abase + (size_t)row * DIM + colg;
            bsrc[pass] = Bbase + (size_t)row * DIM + colg;
            adst[pass] = &Al[0][0] + c * 8;
            bdst[pass] = &Bl[0][0] + c * 8;
        }
        for (int kt = 0; kt < DIM / 64; ++kt) {
            const int k0 = kt * 64;
            #pragma unroll
            for (int pass = 0; pass < 4; ++pass) {
                gld16(asrc[pass] + k0, adst[pass]);
                gld16(bsrc[pass] + k0, bdst[pass]);
            }
            asm volatile("s_waitcnt vmcnt(0)" ::: "memory");
            __syncthreads();
            #pragma unroll
            for (int kc = 0; kc < 2; ++kc) {
                short8 af[4], bfv[4];
                #pragma unroll
                for (int i = 0; i < 4; ++i) {
                    int ra = wm * 64 + i * 16 + l16;
                    af[i] = *(const short8*)&Al[ra][(kc * 32 + hi * 8) ^ ((ra & 7) << 3)];
                }
                #pragma unroll
                for (int j = 0; j < 4; ++j) {
                    int rb = wn * 64 + j * 16 + l16;
                    bfv[j] = *(const short8*)&Bl[rb][(kc * 32 + hi * 8) ^ ((rb & 7) << 3)];
                }
                #pragma unroll
                for (int i = 0; i < 4; ++i)
                    #pragma unroll
                    for (int j = 0; j < 4; ++j)
                        acc[i][j] = mfma16(af[i], bfv[j], acc[i][j]);
            }
            __syncthreads();
        }
    } else {
        const int row2 = t >> 1, part = t & 1;
        const int swz = (row2 & 7) << 3;
        const int cb = part * 32;
        const float* X = (z == 0) ? Xq : (z == 1) ? Xk : Xv;
        const float* Asrc_f = X + (size_t)(m0 + row2) * DIM + cb;
        const unsigned short* Bsrc = W + (size_t)(n0 + row2) * DIM + cb;

        short8 na[4], nbv[4];
        auto ldA = [&](int k0, int i) {
            float4 f0 = *(const float4*)(Asrc_f + k0 + i * 8);
            float4 f1 = *(const float4*)(Asrc_f + k0 + i * 8 + 4);
            union { unsigned int u[4]; short8 s8; } pk;
            pk.u[0] = bfpk(f0.x, f0.y); pk.u[1] = bfpk(f0.z, f0.w);
            pk.u[2] = bfpk(f1.x, f1.y); pk.u[3] = bfpk(f1.z, f1.w);
            return pk.s8;
        };
        #pragma unroll
        for (int i = 0; i < 4; ++i) {
            na[i]  = ldA(0, i);
            nbv[i] = *(const short8*)(Bsrc + i * 8);
        }
        #pragma unroll
        for (int i = 0; i < 4; ++i) {
            *(short8*)&Al[row2][(cb + i * 8) ^ swz] = na[i];
            *(short8*)&Bl[row2][(cb + i * 8) ^ swz] = nbv[i];
        }
        __syncthreads();
        for (int kt = 0; kt < DIM / 64; ++kt) {
            if (kt < DIM / 64 - 1) {
                const int k0n = (kt + 1) * 64;
                #pragma unroll
                for (int i = 0; i < 4; ++i) {
                    na[i]  = ldA(k0n, i);
                    nbv[i] = *(const short8*)(Bsrc + k0n + i * 8);
                }
            }
            #pragma unroll
            for (int kc = 0; kc < 2; ++kc) {
                short8 af[4], bfv[4];
                #pragma unroll
                for (int i = 0; i < 4; ++i) {
                    int ra = wm * 64 + i * 16 + l16;
                    af[i] = *(const short8*)&Al[ra][(kc * 32 + hi * 8) ^ ((ra & 7) << 3)];
                }
                #pragma unroll
                for (int j = 0; j < 4; ++j) {
                    int rb = wn * 64 + j * 16 + l16;
                    bfv[j] = *(const short8*)&Bl[rb][(kc * 32 + hi * 8) ^ ((rb & 7) << 3)];
                }
                #pragma unroll
                for (int i = 0; i < 4; ++i)
                    #pragma unroll
                    for (int j = 0; j < 4; ++j)
                        acc[i][j] = mfma16(af[i], bfv[j], acc[i][j]);
            }
            __syncthreads();
            if (kt < DIM / 64 - 1) {
                #pragma unroll
                for (int i = 0; i < 4; ++i) {
                    *(short8*)&Al[row2][(cb + i * 8) ^ swz] = na[i];
                    *(short8*)&Bl[row2][(cb + i * 8) ^ swz] = nbv[i];
                }
            }
            __syncthreads();
        }
    }

    float bj[4];
    #pragma unroll
    for (int j = 0; j < 4; ++j) bj[j] = bias[n0 + wn * 64 + j * 16 + l16];

    if (z == 2) {
        #pragma unroll
        for (int i = 0; i < 4; ++i) {
            int mrow0 = m0 + wm * 64 + i * 16 + hi * 4;
            int bb = mrow0 >> 11, s = mrow0 & (SEQ - 1);
            #pragma unroll
            for (int r = 0; r < 4; ++r) {
                int p_ = pos[(size_t)bb * SEQ + s + r];
                if (p_ < 0) continue;
                #pragma unroll
                for (int j = 0; j < 4; ++j) {
                    int n = n0 + wn * 64 + j * 16 + l16;
                    int dn = n & 63, hh = n >> 6;
                    int scol = (p_ & ~31) | ((((p_ >> 3) & 3) ^ ((dn >> 1) & 3)) << 3)
                             | (p_ & 7);
                    Vt[((size_t)(bb * NH + hh) * DH + dn) * SEQ + scol] =
                        bfu(acc[i][j][r] + bj[j]);
                }
            }
        }
    } else if (z == 1) {
        #pragma unroll
        for (int i = 0; i < 4; ++i) {
            int mrow0 = m0 + wm * 64 + i * 16 + hi * 4;
            int bb = mrow0 >> 11, s = mrow0 & (SEQ - 1);
            #pragma unroll
            for (int r = 0; r < 4; ++r) {
                int p_ = pos[(size_t)bb * SEQ + s + r];
                if (p_ < 0) continue;
                #pragma unroll
                for (int j = 0; j < 4; ++j) {
                    int n = n0 + wn * 64 + j * 16 + l16;
                    int hh = n >> 6, d = n & 63;
                    int dsw = (d & 7) | ((((d >> 3) ^ (p_ & 7)) & 7) << 3);
                    Kh[((size_t)(bb * NH + hh) * SEQ + p_) * DH + dsw] =
                        bfu(acc[i][j][r] + bj[j]);
                }
            }
        }
    } else {
        const float sc = 0.125f * 1.4426950408889634f;   // fold 1/sqrt(DH)*log2e
        #pragma unroll
        for (int i = 0; i < 4; ++i) {
            #pragma unroll
            for (int j = 0; j < 4; ++j) {
                int n = n0 + wn * 64 + j * 16 + l16;
                int hh = n >> 6, d = n & 63;
                #pragma unroll
                for (int r = 0; r < 4; ++r) {
                    int mrow = m0 + wm * 64 + i * 16 + hi * 4 + r;
                    int bb = mrow >> 11, s = mrow & (SEQ - 1);
                    Qh[((size_t)(bb * NH + hh) * SEQ + s) * DH + d] =
                        bfu((acc[i][j][r] + bj[j]) * sc);
                }
            }
        }
    }
}

// ---------------------------------------------------------------------------
// k3: flash attention over COMPACTED K/V (cnt[b] live columns, 32-padded).
//     8 waves x 32 q (QBLK=256), KVBLK=32, LDS 16KB. Waves 0-3 DMA K,
//     4-7 DMA V. SPLIT: halves of ceil(cnt/32) tiles; partials are pure
//     sums (max-free softmax), combined in outproj.
// ---------------------------------------------------------------------------
template<bool SPLIT>
__global__ __launch_bounds__(512) void attn_kernel(
    const unsigned short* __restrict__ Qh,
    const unsigned short* __restrict__ Kh,
    const unsigned short* __restrict__ Vtp,
    const int* __restrict__ cntbuf,
    unsigned short* __restrict__ AO,
    unsigned short* __restrict__ Opart,
    float* __restrict__ lpart)
{
    __shared__ unsigned short Kl[2][32 * 64];    // [s(32)][d(64)]
    __shared__ unsigned short Vl[2][64 * 32];    // [d(64)][s(32)]

    const int t = threadIdx.x, lane = t & 63, w = t >> 6;   // w 0..7
    const int l31 = lane & 31, h32 = lane >> 5;
    const int bh = blockIdx.x, b = bh >> 4, h = bh & (NH - 1);
    const int q0 = blockIdx.y * 256 + w * 32;
    const int half = SPLIT ? blockIdx.z : 0;

    const int cnt = cntbuf[b];
    const int NTt = (cnt + 31) >> 5;             // total tiles
    const int NTh0 = (NTt + 1) >> 1;
    const int t0   = (SPLIT && half) ? NTh0 : 0;
    const int myNT = SPLIT ? (half ? NTt - NTh0 : NTh0) : NTt;

    const unsigned short* Q = Qh + (size_t)bh * SEQ * DH;
    const unsigned short* K = Kh + (size_t)bh * SEQ * DH;
    const unsigned short* V = Vtp + (size_t)bh * DH * SEQ;

    const int cs = (w & 3) * 64 + lane;
    const bool isK = (w < 4);

    short8 qf[4];
    #pragma unroll
    for (int ds = 0; ds < 4; ++ds)
        qf[ds] = *(const short8*)(Q + (size_t)(q0 + l31) * DH + ds * 16 + h32 * 8);

    f32x16 o[2], ol;
    #pragma unroll
    for (int r = 0; r < 16; ++r) { o[0][r] = 0.f; o[1][r] = 0.f; ol[r] = 0.f; }

    {
        const int kb0 = t0 * 32;
        if (isK) gld16(K + (size_t)(kb0 + (cs >> 3)) * DH + (cs & 7) * 8, &Kl[0][cs * 8]);
        else     gld16(V + (size_t)(cs >> 2) * SEQ + kb0 + (cs & 3) * 8,  &Vl[0][cs * 8]);
    }
    asm volatile("s_waitcnt vmcnt(0)" ::: "memory");
    __syncthreads();

    for (int it = 0; it < myNT; ++it) {
        const int tile = t0 + it;
        const int cur = it & 1;
        const int kb = tile * 32;
        const int nt_ = (it + 1 < myNT) ? (tile + 1) : t0;
        const int nkb = nt_ * 32;

        if (isK) gld16(K + (size_t)(nkb + (cs >> 3)) * DH + (cs & 7) * 8, &Kl[cur ^ 1][cs * 8]);
        else     gld16(V + (size_t)(cs >> 2) * SEQ + nkb + (cs & 3) * 8,  &Vl[cur ^ 1][cs * 8]);

        short8 wf[2];
        if (kb + 32 <= cnt) {
            #pragma unroll
            for (int ss = 0; ss < 2; ++ss)
                #pragma unroll
                for (int e = 0; e < 8; ++e) wf[ss][e] = (short)0x3F80;
        } else {
            #pragma unroll
            for (int ss = 0; ss < 2; ++ss)
                #pragma unroll
                for (int e = 0; e < 8; ++e)
                    wf[ss][e] = (short)((kb + ss * 16 + h32 * 8 + e < cnt) ? 0x3F80 : 0);
        }

        f32x16 st;
        #pragma unroll
        for (int r = 0; r < 16; ++r) st[r] = 0.f;
        __builtin_amdgcn_s_setprio(1);
        #pragma unroll
        for (int ds = 0; ds < 4; ++ds) {
            short8 kfr = *(const short8*)
                &Kl[cur][l31 * 64 + (((ds * 2 + h32) ^ (l31 & 7)) * 8)];
            st = mfma32(kfr, qf[ds], st);
        }
        __builtin_amdgcn_s_setprio(0);

        #pragma unroll
        for (int r = 0; r < 16; ++r) st[r] = exp2f(st[r]);

        short8 pa[2];
        #pragma unroll
        for (int ss = 0; ss < 2; ++ss) {
            const int rb = ss * 8;
            unsigned int a0 = bfpk(st[rb + 0], st[rb + 1]);
            unsigned int a1 = bfpk(st[rb + 2], st[rb + 3]);
            unsigned int b0 = bfpk(st[rb + 4], st[rb + 5]);
            unsigned int b1 = bfpk(st[rb + 6], st[rb + 7]);
            asm volatile("v_permlane32_swap_b32 %0, %1" : "+v"(a0), "+v"(b0));
            asm volatile("v_permlane32_swap_b32 %0, %1" : "+v"(a1), "+v"(b1));
            union { unsigned int u[4]; short8 s8; } up;
            up.u[0] = a0; up.u[1] = a1; up.u[2] = b0; up.u[3] = b1;
            pa[ss] = up.s8;
        }

        __builtin_amdgcn_s_setprio(1);
        #pragma unroll
        for (int ss = 0; ss < 2; ++ss) {
            #pragma unroll
            for (int dblk = 0; dblk < 2; ++dblk) {
                int vrow = dblk * 32 + l31;
                short8 vfr = *(const short8*)
                    &Vl[cur][vrow * 32 + (((ss * 2 + h32) ^ ((l31 >> 1) & 3)) * 8)];
                o[dblk] = mfma32(pa[ss], vfr, o[dblk]);
            }
            ol = mfma32(pa[ss], wf[ss], ol);
        }
        __builtin_amdgcn_s_setprio(0);

        asm volatile("s_waitcnt vmcnt(0)" ::: "memory");
        __syncthreads();
    }
    asm volatile("s_waitcnt vmcnt(0)" ::: "memory");   // covers myNT==0 prologue DMA

    if constexpr (SPLIT) {
        #pragma unroll
        for (int dblk = 0; dblk < 2; ++dblk) {
            #pragma unroll
            for (int r = 0; r < 16; ++r) {
                int q = (r & 3) + 8 * (r >> 2) + 4 * h32;
                Opart[(size_t)half * OHALF + (size_t)(b * SEQ + q0 + q) * DIM
                      + h * DH + dblk * 32 + l31] = bfu(o[dblk][r]);
            }
        }
        if (l31 == 0) {
            #pragma unroll
            for (int r = 0; r < 16; ++r) {
                int q = (r & 3) + 8 * (r >> 2) + 4 * h32;
                lpart[(size_t)half * LHALF + bh * SEQ + q0 + q] = ol[r];
            }
        }
    } else {
        float rcl[16];
        #pragma unroll
        for (int r = 0; r < 16; ++r) rcl[r] = 1.0f / ol[r];
        #pragma unroll
        for (int dblk = 0; dblk < 2; ++dblk) {
            #pragma unroll
            for (int r = 0; r < 16; ++r) {
                int q = (r & 3) + 8 * (r >> 2) + 4 * h32;
                AO[(size_t)(b * SEQ + q0 + q) * DIM + h * DH + dblk * 32 + l31] =
                    bfu(o[dblk][r] * rcl[r]);
            }
        }
    }
}

// ---------------------------------------------------------------------------
// k4: output GEMM, 128x64 tiles -> 512 blocks (R13/R14 proven version).
//     SPLIT fuses the half-combine ((O0+O1)/(l0+l1)) into A-staging.
//     Overwrites ALL of d_out (including the pos/cnt scratch).
// ---------------------------------------------------------------------------
template<bool SPLIT>
__global__ __launch_bounds__(256, 3) void outproj_kernel(
    const unsigned short* __restrict__ Op0, const float* __restrict__ lpart,
    const unsigned short* __restrict__ W,
    const float* __restrict__ bias, float* __restrict__ Out)
{
    __shared__ unsigned short Al[128][64];
    __shared__ unsigned short Bl[64][64];

    const int p = blockIdx.x;                   // 0..511
    const int qq = p >> 3;                      // 0..63
    const int mb = (p & 7) | ((qq & 3) << 3);   // 0..31 ; p%8 = mb%8 (XCD)
    const int nb = qq >> 2;                     // 0..15
    const int m0 = mb * 128, n0 = nb * 64;

    const int t = threadIdx.x, lane = t & 63, w = t >> 6;
    const int l16 = lane & 15, hi = lane >> 4;
    const int wm = w >> 1, wn = w & 1;
    const int row2 = t >> 1, part = t & 1;
    const int swzA = (row2 & 7) << 3;
    const int cb = part * 32;
    const int row4 = t >> 2, part4 = t & 3;
    const int swzB = (row4 & 7) << 3;
    const int cb4 = part4 * 16;

    const int arow = m0 + row2;
    const int bb = arow >> 11, sA = arow & (SEQ - 1);
    const unsigned short* Asrc = Op0 + (size_t)arow * DIM + cb;
    const unsigned short* Bsrc = W + (size_t)(n0 + row4) * DIM + cb4;

    f32x4 zero4 = {0.f, 0.f, 0.f, 0.f};
    f32x4 acc[4][2];
    #pragma unroll
    for (int i = 0; i < 4; ++i) { acc[i][0] = zero4; acc[i][1] = zero4; }

    short8 o0[4], o1[4], nbv[2];
    float rlv = 0.f;

    auto load_kt = [&](int kt) {
        const int k0 = kt * 64;
        if constexpr (SPLIT) {
            size_t li = (size_t)(bb * NH + kt) * SEQ + sA;   // head = kt (64-wide cols)
            rlv = 1.0f / (lpart[li] + lpart[(size_t)LHALF + li]);
            #pragma unroll
            for (int i = 0; i < 4; ++i) {
                o0[i] = *(const short8*)(Asrc + k0 + i * 8);
                o1[i] = *(const short8*)(Asrc + (size_t)OHALF + k0 + i * 8);
            }
        } else {
            #pragma unroll
            for (int i = 0; i < 4; ++i)
                o0[i] = *(const short8*)(Asrc + k0 + i * 8);
        }
        #pragma unroll
        for (int c = 0; c < 2; ++c)
            nbv[c] = *(const short8*)(Bsrc + k0 + c * 8);
    };
    auto stage = [&]() {
        #pragma unroll
        for (int i = 0; i < 4; ++i) {
            short8 na;
            if constexpr (SPLIT) {
                union { unsigned int u[4]; short8 s8; } pk;
                #pragma unroll
                for (int j = 0; j < 4; ++j) {
                    float f0 = (bf2f((unsigned short)o0[i][2*j])   + bf2f((unsigned short)o1[i][2*j]))   * rlv;
                    float f1 = (bf2f((unsigned short)o0[i][2*j+1]) + bf2f((unsigned short)o1[i][2*j+1])) * rlv;
                    pk.u[j] = bfpk(f0, f1);
                }
                na = pk.s8;
            } else {
                na = o0[i];
            }
            *(short8*)&Al[row2][(cb + i * 8) ^ swzA] = na;
        }
        #pragma unroll
        for (int c = 0; c < 2; ++c)
            *(short8*)&Bl[row4][(cb4 + c * 8) ^ swzB] = nbv[c];
    };

    load_kt(0);
    stage();
    __syncthreads();

    for (int kt = 0; kt < DIM / 64; ++kt) {
        if (kt < DIM / 64 - 1) load_kt(kt + 1);
        #pragma unroll
        for (int kc = 0; kc < 2; ++kc) {
            short8 af[4], bfv[2];
            #pragma unroll
            for (int i = 0; i < 4; ++i) {
                int ra = wm * 64 + i * 16 + l16;
                af[i] = *(const short8*)&Al[ra][(kc * 32 + hi * 8) ^ ((ra & 7) << 3)];
            }
            #pragma unroll
            for (int j = 0; j < 2; ++j) {
                int rb = wn * 32 + j * 16 + l16;
                bfv[j] = *(const short8*)&Bl[rb][(kc * 32 + hi * 8) ^ ((rb & 7) << 3)];
            }
            #pragma unroll
            for (int i = 0; i < 4; ++i)
                #pragma unroll
                for (int j = 0; j < 2; ++j)
                    acc[i][j] = mfma16(af[i], bfv[j], acc[i][j]);
        }
        __syncthreads();
        if (kt < DIM / 64 - 1) {
            stage();
        }
        __syncthreads();
    }

    float bj[2];
    #pragma unroll
    for (int j = 0; j < 2; ++j) bj[j] = bias[n0 + wn * 32 + j * 16 + l16];
    #pragma unroll
    for (int i = 0; i < 4; ++i) {
        #pragma unroll
        for (int j = 0; j < 2; ++j) {
            int n = n0 + wn * 32 + j * 16 + l16;
            #pragma unroll
            for (int r = 0; r < 4; ++r) {
                int m = m0 + wm * 64 + i * 16 + hi * 4 + r;
                Out[(size_t)m * DIM + n] = acc[i][j][r] + bj[j];
            }
        }
    }
}

// ---------------------------------------------------------------------------
extern "C" void kernel_launch(void* const* d_in, const int* in_sizes, int n_in,
                              void* d_out, int out_size, void* d_ws, size_t ws_size,
                              hipStream_t stream) {
    const float* query = (const float*)d_in[0];
    const float* key   = (const float*)d_in[1];
    const float* value = (const float*)d_in[2];
    const float* mask  = (const float*)d_in[3];
    const float* Wq    = (const float*)d_in[4];
    const float* bq    = (const float*)d_in[5];
    const float* Wk    = (const float*)d_in[6];
    const float* bk    = (const float*)d_in[7];
    const float* Wv    = (const float*)d_in[8];
    const float* bv    = (const float*)d_in[9];
    const float* Wo    = (const float*)d_in[10];
    const float* bo    = (const float*)d_in[11];
    float* out = (float*)d_out;

    char* ws = (char*)d_ws;
    unsigned short* Wt    = (unsigned short*)(ws);                            //  8 MB
    unsigned short* Qh    = (unsigned short*)(ws + (size_t)8  * 1024 * 1024); //  8 MB
    unsigned short* Kh    = (unsigned short*)(ws + (size_t)16 * 1024 * 1024); //  8 MB compact+swz
    unsigned short* Vt    = (unsigned short*)(ws + (size_t)24 * 1024 * 1024); //  8 MB compact+swz
    unsigned short* Opart = (unsigned short*)(ws + (size_t)32 * 1024 * 1024); // 16 MB (2 halves)
    float*          lpart = (float*)         (ws + (size_t)48 * 1024 * 1024); // 0.5 MB (written
                                                                              //   AFTER Xbf dead)
    unsigned short* Xbf   = (unsigned short*)(ws + (size_t)32 * 1024 * 1024); // 24 MB, dead
                                                                              //   before attn
    // pos/cnt scratch carved from d_out (16 MB): written by mask_scan at call
    // start, read by pad/proj/attn, then outproj overwrites ALL of d_out.
    int* pos  = (int*)d_out;               // 16 KB
    int* cntb = (int*)d_out + 2 * SEQ;     // 8 B
    const unsigned short* WtO = Wt + (size_t)3 * 1024 * 1024;

    wcvt_kernel<<<dim3(256, 4), 256, 0, stream>>>(Wq, Wk, Wv, Wo, Wt);
    mask_scan_kernel<<<2, 256, 0, stream>>>(mask, pos, cntb);
    pad_kernel<<<32, 256, 0, stream>>>(cntb, Kh, Vt);
    if (ws_size >= (size_t)56 * 1024 * 1024) {
        xcvt_kernel<<<dim3(2048, 3), 256, 0, stream>>>(query, key, value, Xbf);
        proj_kernel<true><<<768, 256, 0, stream>>>(Xbf, query, key, value, Wt,
                                                   bq, bk, bv, pos, Qh, Kh, Vt);
        attn_kernel<true><<<dim3(32, 8, 2), 512, 0, stream>>>(Qh, Kh, Vt, cntb,
                                                              nullptr, Opart, lpart);
        outproj_kernel<true><<<512, 256, 0, stream>>>(Opart, lpart, WtO, bo, out);
    } else {
        proj_kernel<false><<<768, 256, 0, stream>>>(nullptr, query, key, value, Wt,
                                                    bq, bk, bv, pos, Qh, Kh, Vt);
        attn_kernel<false><<<dim3(32, 8, 1), 512, 0, stream>>>(Qh, Kh, Vt, cntb,
                                                               Opart, nullptr, nullptr);
        outproj_kernel<false><<<512, 256, 0, stream>>>(Opart, nullptr, WtO, bo, out);
    }
}

// Round 17
// 115.833 us; speedup vs baseline: 1.1001x; 1.0620x over previous
//
#include <hip/hip_runtime.h>
#include <hip/hip_bf16.h>
#include <stdint.h>

// ---------- types ----------
using short8  = __attribute__((ext_vector_type(8))) short;
using f32x4   = __attribute__((ext_vector_type(4))) float;
using f32x16  = __attribute__((ext_vector_type(16))) float;

__device__ inline unsigned short f2bf(float f) {
    union { float f; unsigned int u; } v; v.f = f;
    unsigned int u = v.u;
    unsigned int r = (u + 0x7FFFu + ((u >> 16) & 1u)) >> 16;   // RNE
    return (unsigned short)r;
}

__device__ inline unsigned short bfu(float f) {
    __hip_bfloat16 h = __float2bfloat16(f);
    union { __hip_bfloat16 h; unsigned short u; } c; c.h = h;
    return c.u;
}

__device__ inline float bf2f(unsigned short u) {
    union { unsigned int u; float f; } v; v.u = (unsigned int)u << 16;
    return v.f;
}

// pack two floats to bf16 pair (compiler fuses to v_cvt_pk_bf16_f32)
__device__ inline unsigned int bfpk(float lo, float hi) {
    return (unsigned int)bfu(lo) | ((unsigned int)bfu(hi) << 16);
}

__device__ inline f32x4 mfma16(short8 a, short8 b, f32x4 c) {
    return __builtin_amdgcn_mfma_f32_16x16x32_bf16(a, b, c, 0, 0, 0);
}
__device__ inline f32x16 mfma32(short8 a, short8 b, f32x16 c) {
    return __builtin_amdgcn_mfma_f32_32x32x16_bf16(a, b, c, 0, 0, 0);
}

// async global->LDS, 16B per lane: LDS dest = wave-uniform base + lane*16
__device__ inline void gld16(const void* g, void* l) {
    __builtin_amdgcn_global_load_lds(
        (const __attribute__((address_space(1))) unsigned int*)g,
        (__attribute__((address_space(3))) unsigned int*)l, 16, 0, 0);
}

// B=2, S=2048, D=1024, H=16, DH=64
#define SEQ 2048
#define DIM 1024
#define NH  16
#define DH  64
#define MROWS 4096      // B*S
#define OHALF 4194304   // B*S*DIM elems per split half
#define LHALF 65536     // B*NH*SEQ elems per split half

// ---------------------------------------------------------------------------
// k0 (merged prep): one launch covering
//   blocks [0,2)        : mask scan  -> pos, cnt
//   blocks [2,34)       : pad tail 32-tile of Kh/Vt (self-counts mask zeros)
//   blocks [34,1058)    : wcvt  (4 x 256 tiles of weight transpose+convert)
//   blocks [1058,7202)  : xcvt  (3 x 2048 chunks of X fp32->bf16)
// All writes disjoint; pad runs before proj (launch order), which overwrites
// the live rows of the padded tile.
// ---------------------------------------------------------------------------
__global__ __launch_bounds__(256) void prep_kernel(
    const float* __restrict__ mask, int* __restrict__ pos, int* __restrict__ cnt,
    unsigned short* __restrict__ Kh, unsigned short* __restrict__ Vt,
    const float* __restrict__ W0, const float* __restrict__ W1,
    const float* __restrict__ W2, const float* __restrict__ W3,
    unsigned short* __restrict__ Wt,
    const float* __restrict__ Xq, const float* __restrict__ Xk,
    const float* __restrict__ Xv, unsigned short* __restrict__ Xbf)
{
    __shared__ unsigned short tile[64][72];
    __shared__ int sums[256];
    const int bid = blockIdx.x;
    const int t = threadIdx.x;

    if (bid < 2) {
        // ---- mask scan ----
        const int b = bid;
        const float* m = mask + (size_t)b * SEQ;
        int flags[8], s = 0;
        #pragma unroll
        for (int i = 0; i < 8; ++i) {
            flags[i] = (m[t * 8 + i] == 0.0f) ? 1 : 0;
            s += flags[i];
        }
        sums[t] = s;
        __syncthreads();
        if (t == 0) {
            int acc = 0;
            for (int i = 0; i < 256; ++i) { int x = sums[i]; sums[i] = acc; acc += x; }
            cnt[b] = acc;
        }
        __syncthreads();
        int base = sums[t];
        #pragma unroll
        for (int i = 0; i < 8; ++i) {
            pos[(size_t)b * SEQ + t * 8 + i] = flags[i] ? base : -1;
            base += flags[i];
        }
    } else if (bid < 34) {
        // ---- pad (self-counts zeros; no dependency on scan) ----
        const int bh = bid - 2, b = bh >> 4;
        const float* m = mask + (size_t)b * SEQ;
        int s = 0;
        #pragma unroll
        for (int i = 0; i < 8; ++i) s += (m[t * 8 + i] == 0.0f) ? 1 : 0;
        sums[t] = s;
        __syncthreads();
        if (t == 0) {
            int acc = 0;
            for (int i = 0; i < 256; ++i) acc += sums[i];
            sums[0] = acc;
        }
        __syncthreads();
        const int c = sums[0];
        if ((c & 31) != 0) {
            const int base = c & ~31;
            short8 z = {0, 0, 0, 0, 0, 0, 0, 0};
            *(short8*)(Kh + ((size_t)bh * SEQ + base + (t >> 3)) * DH + (t & 7) * 8) = z;
            *(short8*)(Vt + (size_t)bh * DH * SEQ + (size_t)(t >> 2) * SEQ + base
                       + (t & 3) * 8) = z;
        }
    } else if (bid < 34 + 1024) {
        // ---- wcvt: weight fp32 [k][n] -> bf16 Wt [n][k], 64x64 tiles ----
        const int cblk = bid - 34;
        const int wy = cblk >> 8, wx = cblk & 255;
        const float* W = (wy == 0) ? W0 : (wy == 1) ? W1 : (wy == 2) ? W2 : W3;
        unsigned short* out = Wt + (size_t)wy * DIM * DIM;
        const int tk = wx >> 4, tn = wx & 15;
        const int k0 = tk * 64, n0 = tn * 64;

        #pragma unroll
        for (int j = 0; j < 4; ++j) {
            int c = t + j * 256;
            int r = c >> 4, c4 = c & 15;
            float4 v = *(const float4*)(W + (size_t)(k0 + r) * DIM + n0 + c4 * 4);
            tile[c4 * 4 + 0][r] = f2bf(v.x);
            tile[c4 * 4 + 1][r] = f2bf(v.y);
            tile[c4 * 4 + 2][r] = f2bf(v.z);
            tile[c4 * 4 + 3][r] = f2bf(v.w);
        }
        __syncthreads();
        #pragma unroll
        for (int j = 0; j < 2; ++j) {
            int c = t + j * 256;
            int r = c >> 3, c8 = c & 7;
            *(short8*)(out + (size_t)(n0 + r) * DIM + k0 + c8 * 8) =
                *(const short8*)&tile[r][c8 * 8];
        }
    } else {
        // ---- xcvt: X fp32 -> bf16 flat ----
        const int cblk = bid - 1058;
        const int zz = cblk >> 11, xx = cblk & 2047;
        const float* src = (zz == 0) ? Xq : (zz == 1) ? Xk : Xv;
        size_t i8 = ((size_t)xx * 256 + t) * 8;
        float4 v0 = *(const float4*)(src + i8);
        float4 v1 = *(const float4*)(src + i8 + 4);
        union { unsigned int u[4]; short8 s8; } p;
        p.u[0] = bfpk(v0.x, v0.y); p.u[1] = bfpk(v0.z, v0.w);
        p.u[2] = bfpk(v1.x, v1.y); p.u[3] = bfpk(v1.z, v1.w);
        *(short8*)(Xbf + (size_t)zz * MROWS * DIM + i8) = p.s8;
    }
}

// ---------------------------------------------------------------------------
// k2: projection GEMM. BF16A: both operands staged via global_load_lds DMA
//     (linear LDS dest + source-address pre-swizzle; XOR ds_read unchanged).
//     z=0 -> Qh (scaled 0.125*log2e); z=1 -> Kh COMPACTED; z=2 -> Vt
//     COMPACTED transposed.
// ---------------------------------------------------------------------------
template<bool BF16A>
__global__ __launch_bounds__(256, 3) void proj_kernel(
    const unsigned short* __restrict__ Xbf,
    const float* __restrict__ Xq, const float* __restrict__ Xk, const float* __restrict__ Xv,
    const unsigned short* __restrict__ Wt,
    const float* __restrict__ bq, const float* __restrict__ bk, const float* __restrict__ bv,
    const int* __restrict__ pos,
    unsigned short* __restrict__ Qh, unsigned short* __restrict__ Kh,
    unsigned short* __restrict__ Vt)
{
    __shared__ unsigned short Al[128][64];
    __shared__ unsigned short Bl[128][64];

    const int bid = blockIdx.x;
    const int z = bid >> 8;
    const int p = bid & 255;
    const int qq = p >> 3;
    const int mb = (p & 7) | ((qq & 3) << 3);   // 0..31
    const int nb = qq >> 2;                     // 0..7
    const int m0 = mb * 128, n0 = nb * 128;

    const unsigned short* W = Wt + (size_t)z * DIM * DIM;
    const float* bias = (z == 0) ? bq : (z == 1) ? bk : bv;

    const int t = threadIdx.x, lane = t & 63, w = t >> 6;
    const int l16 = lane & 15, hi = lane >> 4;
    const int wm = w >> 1, wn = w & 1;

    f32x4 zero4 = {0.f, 0.f, 0.f, 0.f};
    f32x4 acc[4][4];
    #pragma unroll
    for (int i = 0; i < 4; ++i)
        #pragma unroll
        for (int j = 0; j < 4; ++j) acc[i][j] = zero4;

    if constexpr (BF16A) {
        const unsigned short* Abase = Xbf + (size_t)z * MROWS * DIM + (size_t)m0 * DIM;
        const unsigned short* Bbase = W + (size_t)n0 * DIM;
        const unsigned short* asrc[4];
        const unsigned short* bsrc[4];
        unsigned short* adst[4];
        unsigned short* bdst[4];
        #pragma unroll
        for (int pass = 0; pass < 4; ++pass) {
            int c = pass * 256 + t;
            int row = c >> 3;
            int colg = (((c & 7) ^ (row & 7)) * 8);
            asrc[pass] = Abase + (size_t)row * DIM + colg;
            bsrc[pass] = Bbase + (size_t)row * DIM + colg;
            adst[pass] = &Al[0][0] + c * 8;
            bdst[pass] = &Bl[0][0] + c * 8;
        }
        for (int kt = 0; kt < DIM / 64; ++kt) {
            const int k0 = kt * 64;
            #pragma unroll
            for (int pass = 0; pass < 4; ++pass) {
                gld16(asrc[pass] + k0, adst[pass]);
                gld16(bsrc[pass] + k0, bdst[pass]);
            }
            asm volatile("s_waitcnt vmcnt(0)" ::: "memory");
            __syncthreads();
            #pragma unroll
            for (int kc = 0; kc < 2; ++kc) {
                short8 af[4], bfv[4];
                #pragma unroll
                for (int i = 0; i < 4; ++i) {
                    int ra = wm * 64 + i * 16 + l16;
                    af[i] = *(const short8*)&Al[ra][(kc * 32 + hi * 8) ^ ((ra & 7) << 3)];
                }
                #pragma unroll
                for (int j = 0; j < 4; ++j) {
                    int rb = wn * 64 + j * 16 + l16;
                    bfv[j] = *(const short8*)&Bl[rb][(kc * 32 + hi * 8) ^ ((rb & 7) << 3)];
                }
                #pragma unroll
                for (int i = 0; i < 4; ++i)
                    #pragma unroll
                    for (int j = 0; j < 4; ++j)
                        acc[i][j] = mfma16(af[i], bfv[j], acc[i][j]);
            }
            __syncthreads();
        }
    } else {
        const int row2 = t >> 1, part = t & 1;
        const int swz = (row2 & 7) << 3;
        const int cb = part * 32;
        const float* X = (z == 0) ? Xq : (z == 1) ? Xk : Xv;
        const float* Asrc_f = X + (size_t)(m0 + row2) * DIM + cb;
        const unsigned short* Bsrc = W + (size_t)(n0 + row2) * DIM + cb;

        short8 na[4], nbv[4];
        auto ldA = [&](int k0, int i) {
            float4 f0 = *(const float4*)(Asrc_f + k0 + i * 8);
            float4 f1 = *(const float4*)(Asrc_f + k0 + i * 8 + 4);
            union { unsigned int u[4]; short8 s8; } pk;
            pk.u[0] = bfpk(f0.x, f0.y); pk.u[1] = bfpk(f0.z, f0.w);
            pk.u[2] = bfpk(f1.x, f1.y); pk.u[3] = bfpk(f1.z, f1.w);
            return pk.s8;
        };
        #pragma unroll
        for (int i = 0; i < 4; ++i) {
            na[i]  = ldA(0, i);
            nbv[i] = *(const short8*)(Bsrc + i * 8);
        }
        #pragma unroll
        for (int i = 0; i < 4; ++i) {
            *(short8*)&Al[row2][(cb + i * 8) ^ swz] = na[i];
            *(short8*)&Bl[row2][(cb + i * 8) ^ swz] = nbv[i];
        }
        __syncthreads();
        for (int kt = 0; kt < DIM / 64; ++kt) {
            if (kt < DIM / 64 - 1) {
                const int k0n = (kt + 1) * 64;
                #pragma unroll
                for (int i = 0; i < 4; ++i) {
                    na[i]  = ldA(k0n, i);
                    nbv[i] = *(const short8*)(Bsrc + k0n + i * 8);
                }
            }
            #pragma unroll
            for (int kc = 0; kc < 2; ++kc) {
                short8 af[4], bfv[4];
                #pragma unroll
                for (int i = 0; i < 4; ++i) {
                    int ra = wm * 64 + i * 16 + l16;
                    af[i] = *(const short8*)&Al[ra][(kc * 32 + hi * 8) ^ ((ra & 7) << 3)];
                }
                #pragma unroll
                for (int j = 0; j < 4; ++j) {
                    int rb = wn * 64 + j * 16 + l16;
                    bfv[j] = *(const short8*)&Bl[rb][(kc * 32 + hi * 8) ^ ((rb & 7) << 3)];
                }
                #pragma unroll
                for (int i = 0; i < 4; ++i)
                    #pragma unroll
                    for (int j = 0; j < 4; ++j)
                        acc[i][j] = mfma16(af[i], bfv[j], acc[i][j]);
            }
            __syncthreads();
            if (kt < DIM / 64 - 1) {
                #pragma unroll
                for (int i = 0; i < 4; ++i) {
                    *(short8*)&Al[row2][(cb + i * 8) ^ swz] = na[i];
                    *(short8*)&Bl[row2][(cb + i * 8) ^ swz] = nbv[i];
                }
            }
            __syncthreads();
        }
    }

    float bj[4];
    #pragma unroll
    for (int j = 0; j < 4; ++j) bj[j] = bias[n0 + wn * 64 + j * 16 + l16];

    if (z == 2) {
        #pragma unroll
        for (int i = 0; i < 4; ++i) {
            int mrow0 = m0 + wm * 64 + i * 16 + hi * 4;
            int bb = mrow0 >> 11, s = mrow0 & (SEQ - 1);
            #pragma unroll
            for (int r = 0; r < 4; ++r) {
                int p_ = pos[(size_t)bb * SEQ + s + r];
                if (p_ < 0) continue;
                #pragma unroll
                for (int j = 0; j < 4; ++j) {
                    int n = n0 + wn * 64 + j * 16 + l16;
                    int dn = n & 63, hh = n >> 6;
                    int scol = (p_ & ~31) | ((((p_ >> 3) & 3) ^ ((dn >> 1) & 3)) << 3)
                             | (p_ & 7);
                    Vt[((size_t)(bb * NH + hh) * DH + dn) * SEQ + scol] =
                        bfu(acc[i][j][r] + bj[j]);
                }
            }
        }
    } else if (z == 1) {
        #pragma unroll
        for (int i = 0; i < 4; ++i) {
            int mrow0 = m0 + wm * 64 + i * 16 + hi * 4;
            int bb = mrow0 >> 11, s = mrow0 & (SEQ - 1);
            #pragma unroll
            for (int r = 0; r < 4; ++r) {
                int p_ = pos[(size_t)bb * SEQ + s + r];
                if (p_ < 0) continue;
                #pragma unroll
                for (int j = 0; j < 4; ++j) {
                    int n = n0 + wn * 64 + j * 16 + l16;
                    int hh = n >> 6, d = n & 63;
                    int dsw = (d & 7) | ((((d >> 3) ^ (p_ & 7)) & 7) << 3);
                    Kh[((size_t)(bb * NH + hh) * SEQ + p_) * DH + dsw] =
                        bfu(acc[i][j][r] + bj[j]);
                }
            }
        }
    } else {
        const float sc = 0.125f * 1.4426950408889634f;   // fold 1/sqrt(DH)*log2e
        #pragma unroll
        for (int i = 0; i < 4; ++i) {
            #pragma unroll
            for (int j = 0; j < 4; ++j) {
                int n = n0 + wn * 64 + j * 16 + l16;
                int hh = n >> 6, d = n & 63;
                #pragma unroll
                for (int r = 0; r < 4; ++r) {
                    int mrow = m0 + wm * 64 + i * 16 + hi * 4 + r;
                    int bb = mrow >> 11, s = mrow & (SEQ - 1);
                    Qh[((size_t)(bb * NH + hh) * SEQ + s) * DH + d] =
                        bfu((acc[i][j][r] + bj[j]) * sc);
                }
            }
        }
    }
}

// ---------------------------------------------------------------------------
// k3: flash attention over COMPACTED K/V (cnt[b] live columns, 32-padded).
//     8 waves x 32 q (QBLK=256), KVBLK=32, LDS 16KB. Waves 0-3 DMA K,
//     4-7 DMA V. SPLIT: halves of ceil(cnt/32) tiles; partials are pure
//     sums (max-free softmax), combined in outproj.
// ---------------------------------------------------------------------------
template<bool SPLIT>
__global__ __launch_bounds__(512) void attn_kernel(
    const unsigned short* __restrict__ Qh,
    const unsigned short* __restrict__ Kh,
    const unsigned short* __restrict__ Vtp,
    const int* __restrict__ cntbuf,
    unsigned short* __restrict__ AO,
    unsigned short* __restrict__ Opart,
    float* __restrict__ lpart)
{
    __shared__ unsigned short Kl[2][32 * 64];    // [s(32)][d(64)]
    __shared__ unsigned short Vl[2][64 * 32];    // [d(64)][s(32)]

    const int t = threadIdx.x, lane = t & 63, w = t >> 6;   // w 0..7
    const int l31 = lane & 31, h32 = lane >> 5;
    const int bh = blockIdx.x, b = bh >> 4, h = bh & (NH - 1);
    const int q0 = blockIdx.y * 256 + w * 32;
    const int half = SPLIT ? blockIdx.z : 0;

    const int cnt = cntbuf[b];
    const int NTt = (cnt + 31) >> 5;             // total tiles
    const int NTh0 = (NTt + 1) >> 1;
    const int t0   = (SPLIT && half) ? NTh0 : 0;
    const int myNT = SPLIT ? (half ? NTt - NTh0 : NTh0) : NTt;

    const unsigned short* Q = Qh + (size_t)bh * SEQ * DH;
    const unsigned short* K = Kh + (size_t)bh * SEQ * DH;
    const unsigned short* V = Vtp + (size_t)bh * DH * SEQ;

    const int cs = (w & 3) * 64 + lane;
    const bool isK = (w < 4);

    short8 qf[4];
    #pragma unroll
    for (int ds = 0; ds < 4; ++ds)
        qf[ds] = *(const short8*)(Q + (size_t)(q0 + l31) * DH + ds * 16 + h32 * 8);

    f32x16 o[2], ol;
    #pragma unroll
    for (int r = 0; r < 16; ++r) { o[0][r] = 0.f; o[1][r] = 0.f; ol[r] = 0.f; }

    {
        const int kb0 = t0 * 32;
        if (isK) gld16(K + (size_t)(kb0 + (cs >> 3)) * DH + (cs & 7) * 8, &Kl[0][cs * 8]);
        else     gld16(V + (size_t)(cs >> 2) * SEQ + kb0 + (cs & 3) * 8,  &Vl[0][cs * 8]);
    }
    asm volatile("s_waitcnt vmcnt(0)" ::: "memory");
    __syncthreads();

    for (int it = 0; it < myNT; ++it) {
        const int tile = t0 + it;
        const int cur = it & 1;
        const int kb = tile * 32;
        const int nt_ = (it + 1 < myNT) ? (tile + 1) : t0;
        const int nkb = nt_ * 32;

        if (isK) gld16(K + (size_t)(nkb + (cs >> 3)) * DH + (cs & 7) * 8, &Kl[cur ^ 1][cs * 8]);
        else     gld16(V + (size_t)(cs >> 2) * SEQ + nkb + (cs & 3) * 8,  &Vl[cur ^ 1][cs * 8]);

        short8 wf[2];
        if (kb + 32 <= cnt) {
            #pragma unroll
            for (int ss = 0; ss < 2; ++ss)
                #pragma unroll
                for (int e = 0; e < 8; ++e) wf[ss][e] = (short)0x3F80;
        } else {
            #pragma unroll
            for (int ss = 0; ss < 2; ++ss)
                #pragma unroll
                for (int e = 0; e < 8; ++e)
                    wf[ss][e] = (short)((kb + ss * 16 + h32 * 8 + e < cnt) ? 0x3F80 : 0);
        }

        f32x16 st;
        #pragma unroll
        for (int r = 0; r < 16; ++r) st[r] = 0.f;
        __builtin_amdgcn_s_setprio(1);
        #pragma unroll
        for (int ds = 0; ds < 4; ++ds) {
            short8 kfr = *(const short8*)
                &Kl[cur][l31 * 64 + (((ds * 2 + h32) ^ (l31 & 7)) * 8)];
            st = mfma32(kfr, qf[ds], st);
        }
        __builtin_amdgcn_s_setprio(0);

        #pragma unroll
        for (int r = 0; r < 16; ++r) st[r] = exp2f(st[r]);

        short8 pa[2];
        #pragma unroll
        for (int ss = 0; ss < 2; ++ss) {
            const int rb = ss * 8;
            unsigned int a0 = bfpk(st[rb + 0], st[rb + 1]);
            unsigned int a1 = bfpk(st[rb + 2], st[rb + 3]);
            unsigned int b0 = bfpk(st[rb + 4], st[rb + 5]);
            unsigned int b1 = bfpk(st[rb + 6], st[rb + 7]);
            asm volatile("v_permlane32_swap_b32 %0, %1" : "+v"(a0), "+v"(b0));
            asm volatile("v_permlane32_swap_b32 %0, %1" : "+v"(a1), "+v"(b1));
            union { unsigned int u[4]; short8 s8; } up;
            up.u[0] = a0; up.u[1] = a1; up.u[2] = b0; up.u[3] = b1;
            pa[ss] = up.s8;
        }

        __builtin_amdgcn_s_setprio(1);
        #pragma unroll
        for (int ss = 0; ss < 2; ++ss) {
            #pragma unroll
            for (int dblk = 0; dblk < 2; ++dblk) {
                int vrow = dblk * 32 + l31;
                short8 vfr = *(const short8*)
                    &Vl[cur][vrow * 32 + (((ss * 2 + h32) ^ ((l31 >> 1) & 3)) * 8)];
                o[dblk] = mfma32(pa[ss], vfr, o[dblk]);
            }
            ol = mfma32(pa[ss], wf[ss], ol);
        }
        __builtin_amdgcn_s_setprio(0);

        asm volatile("s_waitcnt vmcnt(0)" ::: "memory");
        __syncthreads();
    }
    asm volatile("s_waitcnt vmcnt(0)" ::: "memory");   // covers myNT==0 prologue DMA

    if constexpr (SPLIT) {
        #pragma unroll
        for (int dblk = 0; dblk < 2; ++dblk) {
            #pragma unroll
            for (int r = 0; r < 16; ++r) {
                int q = (r & 3) + 8 * (r >> 2) + 4 * h32;
                Opart[(size_t)half * OHALF + (size_t)(b * SEQ + q0 + q) * DIM
                      + h * DH + dblk * 32 + l31] = bfu(o[dblk][r]);
            }
        }
        if (l31 == 0) {
            #pragma unroll
            for (int r = 0; r < 16; ++r) {
                int q = (r & 3) + 8 * (r >> 2) + 4 * h32;
                lpart[(size_t)half * LHALF + bh * SEQ + q0 + q] = ol[r];
            }
        }
    } else {
        float rcl[16];
        #pragma unroll
        for (int r = 0; r < 16; ++r) rcl[r] = 1.0f / ol[r];
        #pragma unroll
        for (int dblk = 0; dblk < 2; ++dblk) {
            #pragma unroll
            for (int r = 0; r < 16; ++r) {
                int q = (r & 3) + 8 * (r >> 2) + 4 * h32;
                AO[(size_t)(b * SEQ + q0 + q) * DIM + h * DH + dblk * 32 + l31] =
                    bfu(o[dblk][r] * rcl[r]);
            }
        }
    }
}

// ---------------------------------------------------------------------------
// k4: output GEMM, 128x64 tiles -> 512 blocks (proven version).
//     SPLIT fuses the half-combine ((O0+O1)/(l0+l1)) into A-staging.
//     Overwrites ALL of d_out (including the pos/cnt scratch).
// ---------------------------------------------------------------------------
template<bool SPLIT>
__global__ __launch_bounds__(256, 3) void outproj_kernel(
    const unsigned short* __restrict__ Op0, const float* __restrict__ lpart,
    const unsigned short* __restrict__ W,
    const float* __restrict__ bias, float* __restrict__ Out)
{
    __shared__ unsigned short Al[128][64];
    __shared__ unsigned short Bl[64][64];

    const int p = blockIdx.x;                   // 0..511
    const int qq = p >> 3;                      // 0..63
    const int mb = (p & 7) | ((qq & 3) << 3);   // 0..31 ; p%8 = mb%8 (XCD)
    const int nb = qq >> 2;                     // 0..15
    const int m0 = mb * 128, n0 = nb * 64;

    const int t = threadIdx.x, lane = t & 63, w = t >> 6;
    const int l16 = lane & 15, hi = lane >> 4;
    const int wm = w >> 1, wn = w & 1;
    const int row2 = t >> 1, part = t & 1;
    const int swzA = (row2 & 7) << 3;
    const int cb = part * 32;
    const int row4 = t >> 2, part4 = t & 3;
    const int swzB = (row4 & 7) << 3;
    const int cb4 = part4 * 16;

    const int arow = m0 + row2;
    const int bb = arow >> 11, sA = arow & (SEQ - 1);
    const unsigned short* Asrc = Op0 + (size_t)arow * DIM + cb;
    const unsigned short* Bsrc = W + (size_t)(n0 + row4) * DIM + cb4;

    f32x4 zero4 = {0.f, 0.f, 0.f, 0.f};
    f32x4 acc[4][2];
    #pragma unroll
    for (int i = 0; i < 4; ++i) { acc[i][0] = zero4; acc[i][1] = zero4; }

    short8 o0[4], o1[4], nbv[2];
    float rlv = 0.f;

    auto load_kt = [&](int kt) {
        const int k0 = kt * 64;
        if constexpr (SPLIT) {
            size_t li = (size_t)(bb * NH + kt) * SEQ + sA;   // head = kt (64-wide cols)
            rlv = 1.0f / (lpart[li] + lpart[(size_t)LHALF + li]);
            #pragma unroll
            for (int i = 0; i < 4; ++i) {
                o0[i] = *(const short8*)(Asrc + k0 + i * 8);
                o1[i] = *(const short8*)(Asrc + (size_t)OHALF + k0 + i * 8);
            }
        } else {
            #pragma unroll
            for (int i = 0; i < 4; ++i)
                o0[i] = *(const short8*)(Asrc + k0 + i * 8);
        }
        #pragma unroll
        for (int c = 0; c < 2; ++c)
            nbv[c] = *(const short8*)(Bsrc + k0 + c * 8);
    };
    auto stage = [&]() {
        #pragma unroll
        for (int i = 0; i < 4; ++i) {
            short8 na;
            if constexpr (SPLIT) {
                union { unsigned int u[4]; short8 s8; } pk;
                #pragma unroll
                for (int j = 0; j < 4; ++j) {
                    float f0 = (bf2f((unsigned short)o0[i][2*j])   + bf2f((unsigned short)o1[i][2*j]))   * rlv;
                    float f1 = (bf2f((unsigned short)o0[i][2*j+1]) + bf2f((unsigned short)o1[i][2*j+1])) * rlv;
                    pk.u[j] = bfpk(f0, f1);
                }
                na = pk.s8;
            } else {
                na = o0[i];
            }
            *(short8*)&Al[row2][(cb + i * 8) ^ swzA] = na;
        }
        #pragma unroll
        for (int c = 0; c < 2; ++c)
            *(short8*)&Bl[row4][(cb4 + c * 8) ^ swzB] = nbv[c];
    };

    load_kt(0);
    stage();
    __syncthreads();

    for (int kt = 0; kt < DIM / 64; ++kt) {
        if (kt < DIM / 64 - 1) load_kt(kt + 1);
        #pragma unroll
        for (int kc = 0; kc < 2; ++kc) {
            short8 af[4], bfv[2];
            #pragma unroll
            for (int i = 0; i < 4; ++i) {
                int ra = wm * 64 + i * 16 + l16;
                af[i] = *(const short8*)&Al[ra][(kc * 32 + hi * 8) ^ ((ra & 7) << 3)];
            }
            #pragma unroll
            for (int j = 0; j < 2; ++j) {
                int rb = wn * 32 + j * 16 + l16;
                bfv[j] = *(const short8*)&Bl[rb][(kc * 32 + hi * 8) ^ ((rb & 7) << 3)];
            }
            #pragma unroll
            for (int i = 0; i < 4; ++i)
                #pragma unroll
                for (int j = 0; j < 2; ++j)
                    acc[i][j] = mfma16(af[i], bfv[j], acc[i][j]);
        }
        __syncthreads();
        if (kt < DIM / 64 - 1) {
            stage();
        }
        __syncthreads();
    }

    float bj[2];
    #pragma unroll
    for (int j = 0; j < 2; ++j) bj[j] = bias[n0 + wn * 32 + j * 16 + l16];
    #pragma unroll
    for (int i = 0; i < 4; ++i) {
        #pragma unroll
        for (int j = 0; j < 2; ++j) {
            int n = n0 + wn * 32 + j * 16 + l16;
            #pragma unroll
            for (int r = 0; r < 4; ++r) {
                int m = m0 + wm * 64 + i * 16 + hi * 4 + r;
                Out[(size_t)m * DIM + n] = acc[i][j][r] + bj[j];
            }
        }
    }
}

// ---------------------------------------------------------------------------
extern "C" void kernel_launch(void* const* d_in, const int* in_sizes, int n_in,
                              void* d_out, int out_size, void* d_ws, size_t ws_size,
                              hipStream_t stream) {
    const float* query = (const float*)d_in[0];
    const float* key   = (const float*)d_in[1];
    const float* value = (const float*)d_in[2];
    const float* mask  = (const float*)d_in[3];
    const float* Wq    = (const float*)d_in[4];
    const float* bq    = (const float*)d_in[5];
    const float* Wk    = (const float*)d_in[6];
    const float* bk    = (const float*)d_in[7];
    const float* Wv    = (const float*)d_in[8];
    const float* bv    = (const float*)d_in[9];
    const float* Wo    = (const float*)d_in[10];
    const float* bo    = (const float*)d_in[11];
    float* out = (float*)d_out;

    char* ws = (char*)d_ws;
    unsigned short* Wt    = (unsigned short*)(ws);                            //  8 MB
    unsigned short* Qh    = (unsigned short*)(ws + (size_t)8  * 1024 * 1024); //  8 MB
    unsigned short* Kh    = (unsigned short*)(ws + (size_t)16 * 1024 * 1024); //  8 MB compact+swz
    unsigned short* Vt    = (unsigned short*)(ws + (size_t)24 * 1024 * 1024); //  8 MB compact+swz
    unsigned short* Opart = (unsigned short*)(ws + (size_t)32 * 1024 * 1024); // 16 MB (2 halves)
    float*          lpart = (float*)         (ws + (size_t)48 * 1024 * 1024); // 0.5 MB (written
                                                                              //   AFTER Xbf dead)
    unsigned short* Xbf   = (unsigned short*)(ws + (size_t)32 * 1024 * 1024); // 24 MB, dead
                                                                              //   before attn
    // pos/cnt scratch carved from d_out (16 MB): written by prep at call
    // start, read by proj/attn, then outproj overwrites ALL of d_out.
    int* pos  = (int*)d_out;               // 16 KB
    int* cntb = (int*)d_out + 2 * SEQ;     // 8 B
    const unsigned short* WtO = Wt + (size_t)3 * 1024 * 1024;

    if (ws_size >= (size_t)56 * 1024 * 1024) {
        prep_kernel<<<7202, 256, 0, stream>>>(mask, pos, cntb, Kh, Vt,
                                              Wq, Wk, Wv, Wo, Wt,
                                              query, key, value, Xbf);
        proj_kernel<true><<<768, 256, 0, stream>>>(Xbf, query, key, value, Wt,
                                                   bq, bk, bv, pos, Qh, Kh, Vt);
        attn_kernel<true><<<dim3(32, 8, 2), 512, 0, stream>>>(Qh, Kh, Vt, cntb,
                                                              nullptr, Opart, lpart);
        outproj_kernel<true><<<512, 256, 0, stream>>>(Opart, lpart, WtO, bo, out);
    } else {
        // fallback: no Xbf workspace -> prep covers only blocks [0,1058)
        prep_kernel<<<1058, 256, 0, stream>>>(mask, pos, cntb, Kh, Vt,
                                              Wq, Wk, Wv, Wo, Wt,
                                              query, key, value, nullptr);
        proj_kernel<false><<<768, 256, 0, stream>>>(nullptr, query, key, value, Wt,
                                                    bq, bk, bv, pos, Qh, Kh, Vt);
        attn_kernel<false><<<dim3(32, 8, 1), 512, 0, stream>>>(Qh, Kh, Vt, cntb,
                                                               Opart, nullptr, nullptr);
        outproj_kernel<false><<<512, 256, 0, stream>>>(Opart, nullptr, WtO, bo, out);
    }
}